// Round 1
// baseline (6283.279 us; speedup 1.0000x reference)
//
#include <hip/hip_runtime.h>
#include <cstdint>
#include <cstddef>

#define NM    53
#define NMP   56
#define HD    256
#define BTT   4096
#define TBLK  448

// sScr layout (floats) for k_enc_attn phase 2
#define QK_STRIDE 68
#define DOTS_OFF  (4*NM*QK_STRIDE)            // 14416
#define DOTS_LD   54
#define WJ_OFF    (DOTS_OFF + NM*DOTS_LD)     // 17278
#define HW_OFF    (WJ_OFF + 64)               // 17342
#define SCR_SIZE  (HW_OFF + HD)               // 17598 floats = 70392 B

__device__ __forceinline__ float4 ldg4(const float* p) { return *(const float4*)p; }

// relu((in[56][256] @ W[256][256]) + b) -> out[56][256], rows >= NM forced to 0.
// 448 threads: cg=tid&63 (float4 col group), tg=tid>>6 (8 rows each).
__device__ __forceinline__ void gemm56_relu(const float* __restrict__ in,
                                            float* __restrict__ out,
                                            const float* __restrict__ W,
                                            const float* __restrict__ bias,
                                            int tid)
{
    const int cg = tid & 63;
    const int tg = tid >> 6;        // 0..6
    const int c4 = cg << 2;
    float acc[8][4];
#pragma unroll
    for (int r = 0; r < 8; ++r) { acc[r][0]=0.f; acc[r][1]=0.f; acc[r][2]=0.f; acc[r][3]=0.f; }
    const float* inb = in + tg*8*HD;
#pragma unroll 4
    for (int k = 0; k < HD; ++k) {
        const float4 w = ldg4(W + (size_t)k*HD + c4);
#pragma unroll
        for (int r = 0; r < 8; ++r) {
            const float h = inb[r*HD + k];
            acc[r][0] = fmaf(h, w.x, acc[r][0]);
            acc[r][1] = fmaf(h, w.y, acc[r][1]);
            acc[r][2] = fmaf(h, w.z, acc[r][2]);
            acc[r][3] = fmaf(h, w.w, acc[r][3]);
        }
    }
    const float b0 = bias[c4+0], b1v = bias[c4+1], b2v = bias[c4+2], b3v = bias[c4+3];
#pragma unroll
    for (int r = 0; r < 8; ++r) {
        const int t = tg*8 + r;
        float4 o;
        o.x = fmaxf(acc[r][0] + b0, 0.f);
        o.y = fmaxf(acc[r][1] + b1v, 0.f);
        o.z = fmaxf(acc[r][2] + b2v, 0.f);
        o.w = fmaxf(acc[r][3] + b3v, 0.f);
        if (t >= NM) { o.x = 0.f; o.y = 0.f; o.z = 0.f; o.w = 0.f; }
        *(float4*)(out + t*HD + c4) = o;
    }
}

// ---------------- kernel 1: encoder MLP + attention + mean + out-proj --------
__global__ __launch_bounds__(TBLK) void k_enc_attn(
    const float* __restrict__ x,
    const float* __restrict__ w1, const float* __restrict__ b1,
    const float* __restrict__ w2, const float* __restrict__ b2,
    const float* __restrict__ wqkv,
    const float* __restrict__ wout, const float* __restrict__ bout,
    float* __restrict__ hbar)
{
    const int bt  = blockIdx.x;
    const int tid = threadIdx.x;

    __shared__ __align__(16) float sH2[NMP][HD];      // 57,344 B
    __shared__ __align__(16) float sScr[SCR_SIZE];    // 70,392 B (h1 / qk+dots+wj+hw)
    __shared__ __align__(16) float sObar[512];        //  2,048 B

    // ---- layer 1: h1 = relu(x @ w1 + b1), pad rows zero (h1 lives in sScr) ----
    const float* xrow = x + (size_t)bt * (NM*3);
    for (int idx = tid; idx < NMP*HD; idx += TBLK) {
        const int t = idx >> 8, c = idx & 255;
        float v = 0.f;
        if (t < NM) {
            v = b1[c]
              + xrow[t*3+0] * w1[c]
              + xrow[t*3+1] * w1[HD + c]
              + xrow[t*3+2] * w1[2*HD + c];
            v = fmaxf(v, 0.f);
        }
        sScr[idx] = v;
    }
    __syncthreads();

    // ---- layer 2: h2 = relu(h1 @ w2 + b2) ----
    gemm56_relu(sScr, &sH2[0][0], w2, b2, tid);
    __syncthreads();

    // ---- attention, 4 head pairs; V-GEMM eliminated algebraically ----
    for (int g = 0; g < 4; ++g) {
        // q,k for heads 2g,2g+1: two 128-col passes over wqkv
        {
            const int cg = tid & 31;       // 32 float4 groups = 128 cols
            const int tg = tid >> 5;       // 0..13, 4 rows each
            const int c4 = cg << 2;
            const int hl = cg >> 4;        // local head 0/1
            const int dd = (cg & 15) << 2; // d within head
            const float* inb = &sH2[tg*4][0];
#pragma unroll
            for (int sec = 0; sec < 2; ++sec) {    // 0=q, 1=k
                const int cbase = sec*512 + g*128;
                float acc[4][4];
#pragma unroll
                for (int r = 0; r < 4; ++r) { acc[r][0]=0.f; acc[r][1]=0.f; acc[r][2]=0.f; acc[r][3]=0.f; }
#pragma unroll 4
                for (int k = 0; k < HD; ++k) {
                    const float4 w = ldg4(wqkv + (size_t)k*1536 + cbase + c4);
#pragma unroll
                    for (int r = 0; r < 4; ++r) {
                        const float h = inb[r*HD + k];
                        acc[r][0] = fmaf(h, w.x, acc[r][0]);
                        acc[r][1] = fmaf(h, w.y, acc[r][1]);
                        acc[r][2] = fmaf(h, w.z, acc[r][2]);
                        acc[r][3] = fmaf(h, w.w, acc[r][3]);
                    }
                }
                const int m = sec*2 + hl;          // q0,q1,k0,k1
                float* qkb = sScr + m*NM*QK_STRIDE;
#pragma unroll
                for (int r = 0; r < 4; ++r) {
                    const int t = tg*4 + r;
                    if (t < NM) {
                        float4 o; o.x=acc[r][0]; o.y=acc[r][1]; o.z=acc[r][2]; o.w=acc[r][3];
                        *(float4*)(qkb + t*QK_STRIDE + dd) = o;
                    }
                }
            }
        }
        __syncthreads();

        for (int hl = 0; hl < 2; ++hl) {
            const float* qb = sScr + (0+hl)*NM*QK_STRIDE;
            const float* kb = sScr + (2+hl)*NM*QK_STRIDE;
            // dots[i][j] = 0.125 * q_i . k_j
            for (int idx = tid; idx < NM*NM; idx += TBLK) {
                const int i = idx / NM;
                const int j = idx - i*NM;
                const float* qi = qb + i*QK_STRIDE;
                const float* kj = kb + j*QK_STRIDE;
                float s = 0.f;
#pragma unroll
                for (int d4 = 0; d4 < 16; ++d4) {
                    const float4 a = *(const float4*)(qi + (d4<<2));
                    const float4 c = *(const float4*)(kj + (d4<<2));
                    s = fmaf(a.x, c.x, s); s = fmaf(a.y, c.y, s);
                    s = fmaf(a.z, c.z, s); s = fmaf(a.w, c.w, s);
                }
                sScr[DOTS_OFF + i*DOTS_LD + j] = s * 0.125f;
            }
            __syncthreads();
            // row softmax (one wave per row)
            {
                const int wv = tid >> 6, lane = tid & 63;
                for (int i = wv; i < NM; i += TBLK/64) {
                    const float xv = (lane < NM) ? sScr[DOTS_OFF + i*DOTS_LD + lane] : -3.4e38f;
                    float mx = xv;
#pragma unroll
                    for (int off = 32; off > 0; off >>= 1) mx = fmaxf(mx, __shfl_xor(mx, off));
                    float e = (lane < NM) ? __expf(xv - mx) : 0.f;
                    float sm = e;
#pragma unroll
                    for (int off = 32; off > 0; off >>= 1) sm += __shfl_xor(sm, off);
                    if (lane < NM) sScr[DOTS_OFF + i*DOTS_LD + lane] = e / sm;
                }
            }
            __syncthreads();
            // wj[j] = sum_i attn[i][j]
            for (int j = tid; j < NM; j += TBLK) {
                float s = 0.f;
                for (int i = 0; i < NM; ++i) s += sScr[DOTS_OFF + i*DOTS_LD + j];
                sScr[WJ_OFF + j] = s;
            }
            __syncthreads();
            // hw[k] = sum_j wj[j]*h2[j][k]   (V-GEMM elimination)
            for (int k = tid; k < HD; k += TBLK) {
                float s = 0.f;
                for (int j = 0; j < NM; ++j) s = fmaf(sScr[WJ_OFF + j], sH2[j][k], s);
                sScr[HW_OFF + k] = s;
            }
            __syncthreads();
            // obar[head][d] = hw . Wv[:, head*64+d]
            if (tid < 64) {
                const int head = g*2 + hl;
                const float* wv_ = wqkv + 1024 + head*64 + tid;
                float s = 0.f;
                for (int k = 0; k < HD; ++k) s = fmaf(sScr[HW_OFF + k], wv_[(size_t)k*1536], s);
                sObar[head*64 + tid] = s;
            }
            __syncthreads();
        }
    }

    // ---- out-proj on the nm-mean: hbar = (obar/53) @ wout + bout ----
    if (tid < 64) {
        const int c4 = tid << 2;
        float a0 = bout[c4+0], a1 = bout[c4+1], a2 = bout[c4+2], a3 = bout[c4+3];
        for (int m = 0; m < 512; ++m) {
            const float ob = sObar[m] * (1.f/53.f);
            const float4 w = ldg4(wout + (size_t)m*HD + c4);
            a0 = fmaf(ob, w.x, a0); a1 = fmaf(ob, w.y, a1);
            a2 = fmaf(ob, w.z, a2); a3 = fmaf(ob, w.w, a3);
        }
        float4 o; o.x=a0; o.y=a1; o.z=a2; o.w=a3;
        *(float4*)(hbar + (size_t)bt*HD + c4) = o;
    }
}

// ---------------- kernel 0: conv weight transpose [O][I][3] -> [3][I][O] -----
__global__ void k_transpose_conv(const float* __restrict__ w, float* __restrict__ wT)
{
    const int idx = blockIdx.x*256 + threadIdx.x;
    if (idx < 3*HD*HD) {
        const int o = idx & 255;
        const int i = (idx >> 8) & 255;
        const int s = idx >> 16;
        wT[idx] = w[(size_t)(o*HD + i)*3 + s];
    }
}

// ---------------- kernel 2: encoder convs + projection to z ------------------
__global__ __launch_bounds__(256) void k_enc_conv(
    const float* __restrict__ hbar,
    const float* __restrict__ wc1T, const float* __restrict__ cb1,
    const float* __restrict__ wc2T, const float* __restrict__ cb2,
    const float* __restrict__ wproj, const float* __restrict__ bproj,
    float* __restrict__ z)
{
    const int b = blockIdx.y, chunk = blockIdx.x;
    const int t0 = chunk * 16;
    const int tid = threadIdx.x;
    __shared__ __align__(16) float sIn[22][HD];
    __shared__ __align__(16) float sMid[18][HD];

    for (int idx = tid; idx < 20*HD; idx += 256) {
        const int r = idx >> 8, c = idx & 255;
        const int t = t0 - 2 + r;
        sIn[r][c] = (t >= 0 && t < 128) ? hbar[(size_t)(b*128 + t)*HD + c] : 0.f;
    }
    __syncthreads();
    const int cg = tid & 63, tg = tid >> 6;
    const int c4 = cg << 2;
    // conv1: rows rr=0..17 -> t' = t0-1+rr
    {
        float acc[5][4];
#pragma unroll
        for (int r2 = 0; r2 < 5; ++r2) { acc[r2][0]=0.f; acc[r2][1]=0.f; acc[r2][2]=0.f; acc[r2][3]=0.f; }
        for (int s = 0; s < 3; ++s)
            for (int i = 0; i < HD; ++i) {
                const float4 w = ldg4(wc1T + (size_t)(s*HD + i)*HD + c4);
#pragma unroll
                for (int r2 = 0; r2 < 5; ++r2) {
                    const float v = sIn[tg*5 + r2 + s][i];
                    acc[r2][0] = fmaf(v, w.x, acc[r2][0]);
                    acc[r2][1] = fmaf(v, w.y, acc[r2][1]);
                    acc[r2][2] = fmaf(v, w.z, acc[r2][2]);
                    acc[r2][3] = fmaf(v, w.w, acc[r2][3]);
                }
            }
        const float4 bb = ldg4(cb1 + c4);
#pragma unroll
        for (int r2 = 0; r2 < 5; ++r2) {
            const int rr = tg*5 + r2;
            if (rr < 18) {
                const int tp = t0 - 1 + rr;
                float4 o; o.x=0.f; o.y=0.f; o.z=0.f; o.w=0.f;
                if (tp >= 0 && tp < 128) {
                    o.x = fmaxf(acc[r2][0] + bb.x, 0.f);
                    o.y = fmaxf(acc[r2][1] + bb.y, 0.f);
                    o.z = fmaxf(acc[r2][2] + bb.z, 0.f);
                    o.w = fmaxf(acc[r2][3] + bb.w, 0.f);
                }
                *(float4*)(&sMid[rr][c4]) = o;
            }
        }
    }
    __syncthreads();
    // conv2: rows q=0..15 -> t = t0+q ; write into sIn rows 0..15
    {
        float acc[4][4];
#pragma unroll
        for (int r2 = 0; r2 < 4; ++r2) { acc[r2][0]=0.f; acc[r2][1]=0.f; acc[r2][2]=0.f; acc[r2][3]=0.f; }
        for (int s = 0; s < 3; ++s)
            for (int i = 0; i < HD; ++i) {
                const float4 w = ldg4(wc2T + (size_t)(s*HD + i)*HD + c4);
#pragma unroll
                for (int r2 = 0; r2 < 4; ++r2) {
                    const float v = sMid[tg*4 + r2 + s][i];
                    acc[r2][0] = fmaf(v, w.x, acc[r2][0]);
                    acc[r2][1] = fmaf(v, w.y, acc[r2][1]);
                    acc[r2][2] = fmaf(v, w.z, acc[r2][2]);
                    acc[r2][3] = fmaf(v, w.w, acc[r2][3]);
                }
            }
        const float4 bb = ldg4(cb2 + c4);
#pragma unroll
        for (int r2 = 0; r2 < 4; ++r2) {
            float4 o;
            o.x = fmaxf(acc[r2][0] + bb.x, 0.f);
            o.y = fmaxf(acc[r2][1] + bb.y, 0.f);
            o.z = fmaxf(acc[r2][2] + bb.z, 0.f);
            o.w = fmaxf(acc[r2][3] + bb.w, 0.f);
            *(float4*)(&sIn[tg*4 + r2][c4]) = o;
        }
    }
    __syncthreads();
    // projection: z[t][l] = conv2out[t] @ wproj + bproj
    {
        const int cgp = tid & 15, tgp = tid >> 4;   // 16 l-groups x 16 rows
        const int l4 = cgp << 2;
        float a0 = bproj[l4+0], a1 = bproj[l4+1], a2 = bproj[l4+2], a3 = bproj[l4+3];
        for (int i = 0; i < HD; ++i) {
            const float4 w = ldg4(wproj + (size_t)i*64 + l4);
            const float v = sIn[tgp][i];
            a0 = fmaf(v, w.x, a0); a1 = fmaf(v, w.y, a1);
            a2 = fmaf(v, w.z, a2); a3 = fmaf(v, w.w, a3);
        }
        float4 o; o.x=a0; o.y=a1; o.z=a2; o.w=a3;
        *(float4*)(z + (size_t)(b*128 + t0 + tgp)*64 + l4) = o;
    }
}

// ---------------- kernel 3: VQ loss reduction --------------------------------
__global__ void k_vq_reduce(const float* __restrict__ z,
                            const float* __restrict__ codebook,
                            float* __restrict__ acc)
{
    const int tid = threadIdx.x;
    float s = 0.f;
    for (int idx = blockIdx.x*256 + tid; idx < BTT*64; idx += gridDim.x*256) {
        const float d = z[idx] - codebook[idx & 63];
        s = fmaf(d, d, s);
    }
#pragma unroll
    for (int off = 32; off > 0; off >>= 1) s += __shfl_xor(s, off);
    __shared__ float sred[4];
    if ((tid & 63) == 0) sred[tid >> 6] = s;
    __syncthreads();
    if (tid == 0) atomicAdd(acc, sred[0] + sred[1] + sred[2] + sred[3]);
}

__global__ void k_vq_final(const float* __restrict__ acc, float* __restrict__ out, int out_size)
{
    if (threadIdx.x == 0 && blockIdx.x == 0) {
        const float mse = acc[0] * (1.f / (BTT*64.f));
        out[out_size-2] = 1.25f * mse;   // q_loss + 0.25*e_loss, both equal mse
        out[out_size-1] = 1.0f;          // perplexity: one-hot avg_probs -> exactly 1.0f
    }
}

// ---------------- kernel 4: decoder constant path (5 t-classes) --------------
__global__ __launch_bounds__(256) void k_dec_prefix(
    const float* __restrict__ codebook,
    const float* __restrict__ winit, const float* __restrict__ binit,
    const float* __restrict__ wdc1, const float* __restrict__ bdc1,
    const float* __restrict__ wdc2, const float* __restrict__ bdc2,
    float* __restrict__ dclass)
{
    const int c = threadIdx.x;
    __shared__ float sD[HD];
    __shared__ float sY1[3][HD];
    float v = binit[c];
    for (int l = 0; l < 64; ++l) v = fmaf(codebook[l], winit[l*HD + c], v);
    sD[c] = v;
    __syncthreads();
    float A0 = 0.f, A1 = 0.f, A2 = 0.f;
    for (int i = 0; i < HD; ++i) {
        const float di = sD[i];
        const float* wp = wdc1 + (size_t)c*768 + i*3;
        A0 = fmaf(wp[0], di, A0);
        A1 = fmaf(wp[1], di, A1);
        A2 = fmaf(wp[2], di, A2);
    }
    const float bb = bdc1[c];
    sY1[0][c] = fmaxf(bb + A1 + A2, 0.f);        // t = 0
    sY1[1][c] = fmaxf(bb + A0 + A1 + A2, 0.f);   // 1..126
    sY1[2][c] = fmaxf(bb + A0 + A1, 0.f);        // t = 127
    __syncthreads();
    const int Ls[5] = {-1, 0, 1, 1, 1};
    const int Cs[5] = { 0, 1, 1, 1, 2};
    const int Rs[5] = { 1, 1, 1, 2,-1};
    for (int cls = 0; cls < 5; ++cls) {
        float s = bdc2[c];
        const int li = Ls[cls], ci = Cs[cls], ri = Rs[cls];
        for (int i = 0; i < HD; ++i) {
            const float* wp = wdc2 + (size_t)c*768 + i*3;
            const float Lv = (li >= 0) ? sY1[li][i] : 0.f;
            const float Cv = sY1[ci][i];
            const float Rv = (ri >= 0) ? sY1[ri][i] : 0.f;
            s = fmaf(wp[0], Lv, s);
            s = fmaf(wp[1], Cv, s);
            s = fmaf(wp[2], Rv, s);
        }
        dclass[cls*HD + c] = fmaxf(s, 0.f);
    }
}

// ---------------- kernel 5: decoder generator (seeds + MLP) ------------------
__global__ __launch_bounds__(TBLK) void k_dec_gen(
    const float* __restrict__ seeds,
    const float* __restrict__ dclass,
    const float* __restrict__ g1, const float* __restrict__ gb1,
    const float* __restrict__ g2, const float* __restrict__ gb2,
    const float* __restrict__ g3, const float* __restrict__ gb3,
    float* __restrict__ out)
{
    const int bt  = blockIdx.x;
    const int tid = threadIdx.x;
    const int t   = bt & 127;
    const int cls = (t == 0) ? 0 : (t == 1) ? 1 : (t < 126) ? 2 : (t == 126) ? 3 : 4;

    __shared__ __align__(16) float sA[NMP][HD];
    __shared__ __align__(16) float sB[NMP][HD];
    __shared__ __align__(16) float sD[HD];

    for (int i = tid; i < HD; i += TBLK) sD[i] = dclass[cls*HD + i];
    __syncthreads();

    const float* srow = seeds + (size_t)bt * (NM*HD);
    for (int idx = tid; idx < NMP*(HD/4); idx += TBLK) {
        const int tt = idx >> 6;
        const int c4 = (idx & 63) << 2;
        float4 v; v.x=0.f; v.y=0.f; v.z=0.f; v.w=0.f;
        if (tt < NM) {
            const float4 s4 = ldg4(srow + (size_t)tt*HD + c4);
            v.x = s4.x + sD[c4+0]; v.y = s4.y + sD[c4+1];
            v.z = s4.z + sD[c4+2]; v.w = s4.w + sD[c4+3];
        }
        *(float4*)(&sA[tt][c4]) = v;
    }
    __syncthreads();
    gemm56_relu(&sA[0][0], &sB[0][0], g1, gb1, tid);
    __syncthreads();
    gemm56_relu(&sB[0][0], &sA[0][0], g2, gb2, tid);
    __syncthreads();
    for (int idx = tid; idx < NM*3; idx += TBLK) {
        const int nm = idx / 3, j = idx - nm*3;
        float s = gb3[j];
        const float* pr = &sA[nm][0];
        for (int c = 0; c < HD; ++c) s = fmaf(pr[c], g3[c*3 + j], s);
        out[(size_t)(bt*NM + nm)*3 + j] = s;
    }
}

// ---------------------------------------------------------------------------
extern "C" void kernel_launch(void* const* d_in, const int* in_sizes, int n_in,
                              void* d_out, int out_size, void* d_ws, size_t ws_size,
                              hipStream_t stream)
{
    const float* x      = (const float*)d_in[0];
    const float* seeds  = (const float*)d_in[1];
    const float* w1     = (const float*)d_in[2];
    const float* b1     = (const float*)d_in[3];
    const float* w2     = (const float*)d_in[4];
    const float* b2     = (const float*)d_in[5];
    const float* wqkv   = (const float*)d_in[6];
    const float* wout   = (const float*)d_in[7];
    const float* bout   = (const float*)d_in[8];
    const float* wc1    = (const float*)d_in[9];
    const float* cb1    = (const float*)d_in[10];
    const float* wc2    = (const float*)d_in[11];
    const float* cb2    = (const float*)d_in[12];
    const float* wproj  = (const float*)d_in[13];
    const float* bproj  = (const float*)d_in[14];
    const float* codebook = (const float*)d_in[15];
    const float* winit  = (const float*)d_in[16];
    const float* binit  = (const float*)d_in[17];
    const float* wdc1   = (const float*)d_in[18];
    const float* bdc1   = (const float*)d_in[19];
    const float* wdc2   = (const float*)d_in[20];
    const float* bdc2   = (const float*)d_in[21];
    const float* g1     = (const float*)d_in[22];
    const float* gb1    = (const float*)d_in[23];
    const float* g2     = (const float*)d_in[24];
    const float* gb2    = (const float*)d_in[25];
    const float* g3     = (const float*)d_in[26];
    const float* gb3    = (const float*)d_in[27];

    float* ws     = (float*)d_ws;
    float* hbar   = ws;                  // 4096*256          = 1,048,576 f
    float* zbuf   = ws + 1048576;        // 4096*64           =   262,144 f
    float* wc1T   = ws + 1310720;        // 3*256*256         =   196,608 f
    float* wc2T   = ws + 1507328;        // 3*256*256         =   196,608 f
    float* dclass = ws + 1703936;        // 5*256             =     1,280 f
    float* accp   = ws + 1705216;        // 1 f   (total ~6.8 MB)

    float* out = (float*)d_out;

    hipMemsetAsync(accp, 0, sizeof(float), stream);
    k_transpose_conv<<<768, 256, 0, stream>>>(wc1, wc1T);
    k_transpose_conv<<<768, 256, 0, stream>>>(wc2, wc2T);
    k_dec_prefix<<<1, 256, 0, stream>>>(codebook, winit, binit, wdc1, bdc1, wdc2, bdc2, dclass);
    k_enc_attn<<<BTT, TBLK, 0, stream>>>(x, w1, b1, w2, b2, wqkv, wout, bout, hbar);
    k_enc_conv<<<dim3(8, 32), 256, 0, stream>>>(hbar, wc1T, cb1, wc2T, cb2, wproj, bproj, zbuf);
    k_vq_reduce<<<256, 256, 0, stream>>>(zbuf, codebook, accp);
    k_vq_final<<<1, 64, 0, stream>>>(accp, out, out_size);
    k_dec_gen<<<BTT, TBLK, 0, stream>>>(seeds, dclass, g1, gb1, g2, gb2, g3, gb3, out);
}

// Round 4
// 3386.175 us; speedup vs baseline: 1.8556x; 1.8556x over previous
//
#include <hip/hip_runtime.h>
#include <cstdint>
#include <cstddef>

#define NM    53
#define NMP   56
#define HD    256
#define BTT   4096
#define TBLK  448   // dec_gen only

typedef __attribute__((ext_vector_type(8))) short short8v;
typedef __attribute__((ext_vector_type(4))) float f32x4;
#define MFMA16(a,b,c) __builtin_amdgcn_mfma_f32_16x16x32_bf16(a,b,c,0,0,0)

__device__ __forceinline__ float4 ldg4(const float* p) { return *(const float4*)p; }

__device__ __forceinline__ short f2bf(float f){
    union { float f; uint32_t u; } v; v.f = f;
    uint32_t r = v.u + 0x7fff + ((v.u >> 16) & 1);
    return (short)(r >> 16);
}
__device__ __forceinline__ float bf2f(short s){
    union { uint32_t u; float f; } v; v.u = ((uint32_t)(uint16_t)s) << 16;
    return v.f;
}

// ---------------- prep: bf16-transpose w2 and wqkv(q,k cols) -----------------
// w2T[n][k] = w2[k][n]  (256x256)  |  wqkT[n][k] = wqkv[k][n], n<1024
__global__ void k_prep_bf16(const float* __restrict__ w2, const float* __restrict__ wqkv,
                            short* __restrict__ w2T, short* __restrict__ wqkT)
{
    const int idx = blockIdx.x*256 + threadIdx.x;
    if (idx < 65536) {
        const int n = idx >> 8, k = idx & 255;
        w2T[idx] = f2bf(w2[k*HD + n]);
    } else if (idx < 65536 + 262144) {
        const int j = idx - 65536;
        const int n = j >> 8, k = j & 255;
        wqkT[j] = f2bf(wqkv[(size_t)k*1536 + n]);
    }
}

// ---------------- kernel 1: encoder MLP + attention (bf16 MFMA) --------------
// 256 threads = 4 waves. One bt per block. LDS ~73 KB -> 2 blocks/CU.
__global__ __launch_bounds__(256) void k_enc_attn(
    const float* __restrict__ x,
    const float* __restrict__ w1, const float* __restrict__ b1,
    const float* __restrict__ b2,
    const short* __restrict__ w2T,   // [256][256] bf16 (row n, col k)
    const short* __restrict__ wqkT,  // [1024][256] bf16 (row n, col k)
    const float* __restrict__ wqkv,  // fp32 original (for Wv columns)
    const float* __restrict__ wout, const float* __restrict__ bout,
    float* __restrict__ hbar)
{
    const int bt   = blockIdx.x;
    const int tid  = threadIdx.x;
    const int wv   = tid >> 6;     // wave 0..3
    const int lane = tid & 63;
    const int lr   = lane & 15;    // fragment row/col index
    const int lg   = lane >> 4;    // k-group

    // union scratch: h1b (33792 B) / {q(9216)+k(9216)+dots(17408)} / part(4096)
    __shared__ __align__(16) char  sU[35840];
    __shared__ __align__(16) short sH2b[64*264];              // 33792 B
    __shared__ __align__(16) float sSmall[64+256+512];        //  3328 B
    short* sH1b = (short*)sU;                 // [64][264] bf16
    short* sQ   = (short*)sU;                 // [64][72]  bf16
    short* sK   = (short*)(sU + 9216);        // [64][72]  bf16
    float* sDots= (float*)(sU + 18432);       // [64][68]  f32
    float* sPart= (float*)sU;                 // [4][256]  f32
    float* sWj  = sSmall;
    float* sHw  = sSmall + 64;
    float* sObar= sSmall + 320;

    // ---- P1: h1 = relu(x @ w1 + b1) -> bf16 LDS (pad rows zero) ----
    {
        const float* xr = x + (size_t)bt * (NM*3);
        const float W0 = w1[tid], W1 = w1[HD+tid], W2 = w1[2*HD+tid], B = b1[tid];
        for (int t = 0; t < 64; ++t) {
            float v = 0.f;
            if (t < NM)
                v = fmaxf(fmaf(xr[t*3], W0, fmaf(xr[t*3+1], W1, fmaf(xr[t*3+2], W2, B))), 0.f);
            sH1b[t*264 + tid] = f2bf(v);
        }
    }
    __syncthreads();

    // ---- P2: h2 = relu(h1 @ w2 + b2) -> bf16 LDS, rows>=53 forced 0 ----
    {
        short8v a[8];
#pragma unroll
        for (int ks = 0; ks < 8; ++ks)
            a[ks] = *(const short8v*)(sH1b + (wv*16 + lr)*264 + ks*32 + lg*8);
        for (int nf = 0; nf < 16; ++nf) {
            f32x4 acc = {0.f, 0.f, 0.f, 0.f};
#pragma unroll
            for (int ks = 0; ks < 8; ++ks) {
                const short8v bfr = *(const short8v*)(w2T + (size_t)(nf*16 + lr)*HD + ks*32 + lg*8);
                acc = MFMA16(a[ks], bfr, acc);
            }
            const int n = nf*16 + lr;
            const float bb = b2[n];
#pragma unroll
            for (int r = 0; r < 4; ++r) {
                const int m = wv*16 + lg*4 + r;          // verified C/D row mapping
                const float v = (m < NM) ? fmaxf(acc[r] + bb, 0.f) : 0.f;
                sH2b[m*264 + n] = f2bf(v);
            }
        }
    }
    __syncthreads();

    // preload this wave's A-strip of h2 (reused by all heads)
    short8v ah[8];
#pragma unroll
    for (int ks = 0; ks < 8; ++ks)
        ah[ks] = *(const short8v*)(sH2b + (wv*16 + lr)*264 + ks*32 + lg*8);

    for (int h = 0; h < 8; ++h) {
        // (a) q,k projection for head h (no bias; pad rows stay 0)
#pragma unroll
        for (int sec = 0; sec < 2; ++sec) {
            short* dst = sec ? sK : sQ;
            const short* wb = wqkT + (size_t)(sec*512 + h*64) * HD;
            for (int nf = 0; nf < 4; ++nf) {
                f32x4 acc = {0.f, 0.f, 0.f, 0.f};
#pragma unroll
                for (int ks = 0; ks < 8; ++ks) {
                    const short8v bfr = *(const short8v*)(wb + (size_t)(nf*16 + lr)*HD + ks*32 + lg*8);
                    acc = MFMA16(ah[ks], bfr, acc);
                }
                const int d = nf*16 + lr;
#pragma unroll
                for (int r = 0; r < 4; ++r) {
                    const int m = wv*16 + lg*4 + r;
                    dst[m*72 + d] = f2bf(acc[r]);
                }
            }
        }
        __syncthreads();

        // (b) dots = 0.125 * q @ k^T  (A=q, B=k; same slot->k packing)
        {
            const short8v aq0 = *(const short8v*)(sQ + (wv*16 + lr)*72 + lg*8);
            const short8v aq1 = *(const short8v*)(sQ + (wv*16 + lr)*72 + 32 + lg*8);
#pragma unroll
            for (int nf = 0; nf < 4; ++nf) {
                f32x4 acc = {0.f, 0.f, 0.f, 0.f};
                const short8v bk0 = *(const short8v*)(sK + (nf*16 + lr)*72 + lg*8);
                const short8v bk1 = *(const short8v*)(sK + (nf*16 + lr)*72 + 32 + lg*8);
                acc = MFMA16(aq0, bk0, acc);
                acc = MFMA16(aq1, bk1, acc);
                const int j = nf*16 + lr;
#pragma unroll
                for (int r = 0; r < 4; ++r) {
                    const int i = wv*16 + lg*4 + r;
                    sDots[i*68 + j] = acc[r] * 0.125f;
                }
            }
        }
        __syncthreads();

        // (c) row softmax (one wave per row)
        for (int i = wv; i < NM; i += 4) {
            const float xv = (lane < NM) ? sDots[i*68 + lane] : -3.4e38f;
            float mx = xv;
#pragma unroll
            for (int off = 32; off > 0; off >>= 1) mx = fmaxf(mx, __shfl_xor(mx, off));
            float e = (lane < NM) ? __expf(xv - mx) : 0.f;
            float sm = e;
#pragma unroll
            for (int off = 32; off > 0; off >>= 1) sm += __shfl_xor(sm, off);
            if (lane < NM) sDots[i*68 + lane] = e / sm;
        }
        __syncthreads();

        // (d) wj[j] = sum_i attn[i][j]
        if (tid < NM) {
            float s = 0.f;
            for (int i = 0; i < NM; ++i) s += sDots[i*68 + tid];
            sWj[tid] = s;
        }
        __syncthreads();

        // (e) hw[c] = sum_j wj[j] * h2[j][c]
        {
            float s = 0.f;
            for (int j = 0; j < NM; ++j) s = fmaf(sWj[j], bf2f(sH2b[j*264 + tid]), s);
            sHw[tid] = s;
        }
        __syncthreads();

        // (f) obar[h][d] = hw . Wv[:, h*64+d]  (fp32 weights, coalesced rows)
        if (tid < 64) {
            const float* wvp = wqkv + 1024 + h*64 + tid;
            float s = 0.f;
            for (int c = 0; c < HD; ++c) s = fmaf(sHw[c], wvp[(size_t)c*1536], s);
            sObar[h*64 + tid] = s;
        }
        __syncthreads();
    }

    // ---- P4: hbar = (obar/53) @ wout + bout, split over 4 waves ----
    {
        const int c4 = lane << 2;
        float a0 = 0.f, a1 = 0.f, a2 = 0.f, a3 = 0.f;
        for (int m = wv*128; m < wv*128 + 128; ++m) {
            const float ob = sObar[m] * (1.f/53.f);
            const float4 w = ldg4(wout + (size_t)m*HD + c4);
            a0 = fmaf(ob, w.x, a0); a1 = fmaf(ob, w.y, a1);
            a2 = fmaf(ob, w.z, a2); a3 = fmaf(ob, w.w, a3);
        }
        sPart[wv*256 + c4 + 0] = a0;
        sPart[wv*256 + c4 + 1] = a1;
        sPart[wv*256 + c4 + 2] = a2;
        sPart[wv*256 + c4 + 3] = a3;
    }
    __syncthreads();
    hbar[(size_t)bt*HD + tid] =
        sPart[tid] + sPart[256+tid] + sPart[512+tid] + sPart[768+tid] + bout[tid];
}

// relu((in[56][256] @ W[256][256]) + b) -> out[56][256], rows >= NM forced to 0.
// 448 threads: cg=tid&63 (float4 col group), tg=tid>>6 (8 rows each).
__device__ __forceinline__ void gemm56_relu(const float* __restrict__ in,
                                            float* __restrict__ out,
                                            const float* __restrict__ W,
                                            const float* __restrict__ bias,
                                            int tid)
{
    const int cg = tid & 63;
    const int tg = tid >> 6;        // 0..6
    const int c4 = cg << 2;
    float acc[8][4];
#pragma unroll
    for (int r = 0; r < 8; ++r) { acc[r][0]=0.f; acc[r][1]=0.f; acc[r][2]=0.f; acc[r][3]=0.f; }
    const float* inb = in + tg*8*HD;
#pragma unroll 4
    for (int k = 0; k < HD; ++k) {
        const float4 w = ldg4(W + (size_t)k*HD + c4);
#pragma unroll
        for (int r = 0; r < 8; ++r) {
            const float h = inb[r*HD + k];
            acc[r][0] = fmaf(h, w.x, acc[r][0]);
            acc[r][1] = fmaf(h, w.y, acc[r][1]);
            acc[r][2] = fmaf(h, w.z, acc[r][2]);
            acc[r][3] = fmaf(h, w.w, acc[r][3]);
        }
    }
    const float b0 = bias[c4+0], b1v = bias[c4+1], b2v = bias[c4+2], b3v = bias[c4+3];
#pragma unroll
    for (int r = 0; r < 8; ++r) {
        const int t = tg*8 + r;
        float4 o;
        o.x = fmaxf(acc[r][0] + b0, 0.f);
        o.y = fmaxf(acc[r][1] + b1v, 0.f);
        o.z = fmaxf(acc[r][2] + b2v, 0.f);
        o.w = fmaxf(acc[r][3] + b3v, 0.f);
        if (t >= NM) { o.x = 0.f; o.y = 0.f; o.z = 0.f; o.w = 0.f; }
        *(float4*)(out + t*HD + c4) = o;
    }
}

// ---------------- kernel 0: conv weight transpose [O][I][3] -> [3][I][O] -----
__global__ void k_transpose_conv(const float* __restrict__ w, float* __restrict__ wT)
{
    const int idx = blockIdx.x*256 + threadIdx.x;
    if (idx < 3*HD*HD) {
        const int o = idx & 255;
        const int i = (idx >> 8) & 255;
        const int s = idx >> 16;
        wT[idx] = w[(size_t)(o*HD + i)*3 + s];
    }
}

// ---------------- kernel 2: encoder convs + projection to z ------------------
__global__ __launch_bounds__(256) void k_enc_conv(
    const float* __restrict__ hbar,
    const float* __restrict__ wc1T, const float* __restrict__ cb1,
    const float* __restrict__ wc2T, const float* __restrict__ cb2,
    const float* __restrict__ wproj, const float* __restrict__ bproj,
    float* __restrict__ z)
{
    const int b = blockIdx.y, chunk = blockIdx.x;
    const int t0 = chunk * 16;
    const int tid = threadIdx.x;
    __shared__ __align__(16) float sIn[22][HD];
    __shared__ __align__(16) float sMid[18][HD];

    for (int idx = tid; idx < 20*HD; idx += 256) {
        const int r = idx >> 8, c = idx & 255;
        const int t = t0 - 2 + r;
        sIn[r][c] = (t >= 0 && t < 128) ? hbar[(size_t)(b*128 + t)*HD + c] : 0.f;
    }
    __syncthreads();
    const int cg = tid & 63, tg = tid >> 6;
    const int c4 = cg << 2;
    // conv1: rows rr=0..17 -> t' = t0-1+rr
    {
        float acc[5][4];
#pragma unroll
        for (int r2 = 0; r2 < 5; ++r2) { acc[r2][0]=0.f; acc[r2][1]=0.f; acc[r2][2]=0.f; acc[r2][3]=0.f; }
        for (int s = 0; s < 3; ++s)
            for (int i = 0; i < HD; ++i) {
                const float4 w = ldg4(wc1T + (size_t)(s*HD + i)*HD + c4);
#pragma unroll
                for (int r2 = 0; r2 < 5; ++r2) {
                    const float v = sIn[tg*5 + r2 + s][i];
                    acc[r2][0] = fmaf(v, w.x, acc[r2][0]);
                    acc[r2][1] = fmaf(v, w.y, acc[r2][1]);
                    acc[r2][2] = fmaf(v, w.z, acc[r2][2]);
                    acc[r2][3] = fmaf(v, w.w, acc[r2][3]);
                }
            }
        const float4 bb = ldg4(cb1 + c4);
#pragma unroll
        for (int r2 = 0; r2 < 5; ++r2) {
            const int rr = tg*5 + r2;
            if (rr < 18) {
                const int tp = t0 - 1 + rr;
                float4 o; o.x=0.f; o.y=0.f; o.z=0.f; o.w=0.f;
                if (tp >= 0 && tp < 128) {
                    o.x = fmaxf(acc[r2][0] + bb.x, 0.f);
                    o.y = fmaxf(acc[r2][1] + bb.y, 0.f);
                    o.z = fmaxf(acc[r2][2] + bb.z, 0.f);
                    o.w = fmaxf(acc[r2][3] + bb.w, 0.f);
                }
                *(float4*)(&sMid[rr][c4]) = o;
            }
        }
    }
    __syncthreads();
    // conv2: rows q=0..15 -> t = t0+q ; write into sIn rows 0..15
    {
        float acc[4][4];
#pragma unroll
        for (int r2 = 0; r2 < 4; ++r2) { acc[r2][0]=0.f; acc[r2][1]=0.f; acc[r2][2]=0.f; acc[r2][3]=0.f; }
        for (int s = 0; s < 3; ++s)
            for (int i = 0; i < HD; ++i) {
                const float4 w = ldg4(wc2T + (size_t)(s*HD + i)*HD + c4);
#pragma unroll
                for (int r2 = 0; r2 < 4; ++r2) {
                    const float v = sMid[tg*4 + r2 + s][i];
                    acc[r2][0] = fmaf(v, w.x, acc[r2][0]);
                    acc[r2][1] = fmaf(v, w.y, acc[r2][1]);
                    acc[r2][2] = fmaf(v, w.z, acc[r2][2]);
                    acc[r2][3] = fmaf(v, w.w, acc[r2][3]);
                }
            }
        const float4 bb = ldg4(cb2 + c4);
#pragma unroll
        for (int r2 = 0; r2 < 4; ++r2) {
            float4 o;
            o.x = fmaxf(acc[r2][0] + bb.x, 0.f);
            o.y = fmaxf(acc[r2][1] + bb.y, 0.f);
            o.z = fmaxf(acc[r2][2] + bb.z, 0.f);
            o.w = fmaxf(acc[r2][3] + bb.w, 0.f);
            *(float4*)(&sIn[tg*4 + r2][c4]) = o;
        }
    }
    __syncthreads();
    // projection: z[t][l] = conv2out[t] @ wproj + bproj
    {
        const int cgp = tid & 15, tgp = tid >> 4;   // 16 l-groups x 16 rows
        const int l4 = cgp << 2;
        float a0 = bproj[l4+0], a1 = bproj[l4+1], a2 = bproj[l4+2], a3 = bproj[l4+3];
        for (int i = 0; i < HD; ++i) {
            const float4 w = ldg4(wproj + (size_t)i*64 + l4);
            const float v = sIn[tgp][i];
            a0 = fmaf(v, w.x, a0); a1 = fmaf(v, w.y, a1);
            a2 = fmaf(v, w.z, a2); a3 = fmaf(v, w.w, a3);
        }
        float4 o; o.x=a0; o.y=a1; o.z=a2; o.w=a3;
        *(float4*)(z + (size_t)(b*128 + t0 + tgp)*64 + l4) = o;
    }
}

// ---------------- kernel 3: VQ loss reduction --------------------------------
__global__ void k_vq_reduce(const float* __restrict__ z,
                            const float* __restrict__ codebook,
                            float* __restrict__ acc)
{
    const int tid = threadIdx.x;
    float s = 0.f;
    for (int idx = blockIdx.x*256 + tid; idx < BTT*64; idx += gridDim.x*256) {
        const float d = z[idx] - codebook[idx & 63];
        s = fmaf(d, d, s);
    }
#pragma unroll
    for (int off = 32; off > 0; off >>= 1) s += __shfl_xor(s, off);
    __shared__ float sred[4];
    if ((tid & 63) == 0) sred[tid >> 6] = s;
    __syncthreads();
    if (tid == 0) atomicAdd(acc, sred[0] + sred[1] + sred[2] + sred[3]);
}

__global__ void k_vq_final(const float* __restrict__ acc, float* __restrict__ out, int out_size)
{
    if (threadIdx.x == 0 && blockIdx.x == 0) {
        const float mse = acc[0] * (1.f / (BTT*64.f));
        out[out_size-2] = 1.25f * mse;   // q_loss + 0.25*e_loss, both equal mse
        out[out_size-1] = 1.0f;          // perplexity exactly 1
    }
}

// ---------------- kernel 4: decoder constant path (5 t-classes) --------------
__global__ __launch_bounds__(256) void k_dec_prefix(
    const float* __restrict__ codebook,
    const float* __restrict__ winit, const float* __restrict__ binit,
    const float* __restrict__ wdc1, const float* __restrict__ bdc1,
    const float* __restrict__ wdc2, const float* __restrict__ bdc2,
    float* __restrict__ dclass)
{
    const int c = threadIdx.x;
    __shared__ float sD[HD];
    __shared__ float sY1[3][HD];
    float v = binit[c];
    for (int l = 0; l < 64; ++l) v = fmaf(codebook[l], winit[l*HD + c], v);
    sD[c] = v;
    __syncthreads();
    float A0 = 0.f, A1 = 0.f, A2 = 0.f;
    for (int i = 0; i < HD; ++i) {
        const float di = sD[i];
        const float* wp = wdc1 + (size_t)c*768 + i*3;
        A0 = fmaf(wp[0], di, A0);
        A1 = fmaf(wp[1], di, A1);
        A2 = fmaf(wp[2], di, A2);
    }
    const float bb = bdc1[c];
    sY1[0][c] = fmaxf(bb + A1 + A2, 0.f);        // t = 0
    sY1[1][c] = fmaxf(bb + A0 + A1 + A2, 0.f);   // 1..126
    sY1[2][c] = fmaxf(bb + A0 + A1, 0.f);        // t = 127
    __syncthreads();
    const int Ls[5] = {-1, 0, 1, 1, 1};
    const int Cs[5] = { 0, 1, 1, 1, 2};
    const int Rs[5] = { 1, 1, 1, 2,-1};
    for (int cls = 0; cls < 5; ++cls) {
        float s = bdc2[c];
        const int li = Ls[cls], ci = Cs[cls], ri = Rs[cls];
        for (int i = 0; i < HD; ++i) {
            const float* wp = wdc2 + (size_t)c*768 + i*3;
            const float Lv = (li >= 0) ? sY1[li][i] : 0.f;
            const float Cv = sY1[ci][i];
            const float Rv = (ri >= 0) ? sY1[ri][i] : 0.f;
            s = fmaf(wp[0], Lv, s);
            s = fmaf(wp[1], Cv, s);
            s = fmaf(wp[2], Rv, s);
        }
        dclass[cls*HD + c] = fmaxf(s, 0.f);
    }
}

// ---------------- kernel 5: decoder generator (seeds + MLP, fp32) ------------
__global__ __launch_bounds__(TBLK) void k_dec_gen(
    const float* __restrict__ seeds,
    const float* __restrict__ dclass,
    const float* __restrict__ g1, const float* __restrict__ gb1,
    const float* __restrict__ g2, const float* __restrict__ gb2,
    const float* __restrict__ g3, const float* __restrict__ gb3,
    float* __restrict__ out)
{
    const int bt  = blockIdx.x;
    const int tid = threadIdx.x;
    const int t   = bt & 127;
    const int cls = (t == 0) ? 0 : (t == 1) ? 1 : (t < 126) ? 2 : (t == 126) ? 3 : 4;

    __shared__ __align__(16) float sA[NMP][HD];
    __shared__ __align__(16) float sB[NMP][HD];
    __shared__ __align__(16) float sD[HD];

    for (int i = tid; i < HD; i += TBLK) sD[i] = dclass[cls*HD + i];
    __syncthreads();

    const float* srow = seeds + (size_t)bt * (NM*HD);
    for (int idx = tid; idx < NMP*(HD/4); idx += TBLK) {
        const int tt = idx >> 6;
        const int c4 = (idx & 63) << 2;
        float4 v; v.x=0.f; v.y=0.f; v.z=0.f; v.w=0.f;
        if (tt < NM) {
            const float4 s4 = ldg4(srow + (size_t)tt*HD + c4);
            v.x = s4.x + sD[c4+0]; v.y = s4.y + sD[c4+1];
            v.z = s4.z + sD[c4+2]; v.w = s4.w + sD[c4+3];
        }
        *(float4*)(&sA[tt][c4]) = v;
    }
    __syncthreads();
    gemm56_relu(&sA[0][0], &sB[0][0], g1, gb1, tid);
    __syncthreads();
    gemm56_relu(&sB[0][0], &sA[0][0], g2, gb2, tid);
    __syncthreads();
    for (int idx = tid; idx < NM*3; idx += TBLK) {
        const int nm = idx / 3, j = idx - nm*3;
        float s = gb3[j];
        const float* pr = &sA[nm][0];
        for (int c = 0; c < HD; ++c) s = fmaf(pr[c], g3[c*3 + j], s);
        out[(size_t)(bt*NM + nm)*3 + j] = s;
    }
}

// ---------------------------------------------------------------------------
extern "C" void kernel_launch(void* const* d_in, const int* in_sizes, int n_in,
                              void* d_out, int out_size, void* d_ws, size_t ws_size,
                              hipStream_t stream)
{
    const float* x      = (const float*)d_in[0];
    const float* seeds  = (const float*)d_in[1];
    const float* w1     = (const float*)d_in[2];
    const float* b1     = (const float*)d_in[3];
    const float* w2     = (const float*)d_in[4];
    const float* b2     = (const float*)d_in[5];
    const float* wqkv   = (const float*)d_in[6];
    const float* wout   = (const float*)d_in[7];
    const float* bout   = (const float*)d_in[8];
    const float* wc1    = (const float*)d_in[9];
    const float* cb1    = (const float*)d_in[10];
    const float* wc2    = (const float*)d_in[11];
    const float* cb2    = (const float*)d_in[12];
    const float* wproj  = (const float*)d_in[13];
    const float* bproj  = (const float*)d_in[14];
    const float* codebook = (const float*)d_in[15];
    const float* winit  = (const float*)d_in[16];
    const float* binit  = (const float*)d_in[17];
    const float* wdc1   = (const float*)d_in[18];
    const float* bdc1   = (const float*)d_in[19];
    const float* wdc2   = (const float*)d_in[20];
    const float* bdc2   = (const float*)d_in[21];
    const float* g1     = (const float*)d_in[22];
    const float* gb1    = (const float*)d_in[23];
    const float* g2     = (const float*)d_in[24];
    const float* gb2    = (const float*)d_in[25];
    const float* g3     = (const float*)d_in[26];
    const float* gb3    = (const float*)d_in[27];

    float* ws     = (float*)d_ws;
    float* hbar   = ws;                  // 1,048,576 f
    float* zbuf   = ws + 1048576;        //   262,144 f
    float* wc1T   = ws + 1310720;        //   196,608 f
    float* wc2T   = ws + 1507328;        //   196,608 f
    float* dclass = ws + 1703936;        //     1,280 f
    float* accp   = ws + 1705216;        //         4 f (padded)
    short* w2T    = (short*)(ws + 1705220);            // 65,536 bf16 = 32,768 f
    short* wqkT   = (short*)(ws + 1705220 + 32768);    // 262,144 bf16 = 131,072 f
    // total ~7.5 MB

    float* out = (float*)d_out;

    hipMemsetAsync(accp, 0, sizeof(float), stream);
    k_prep_bf16<<<1280, 256, 0, stream>>>(w2, wqkv, w2T, wqkT);
    k_transpose_conv<<<768, 256, 0, stream>>>(wc1, wc1T);
    k_transpose_conv<<<768, 256, 0, stream>>>(wc2, wc2T);
    k_dec_prefix<<<1, 256, 0, stream>>>(codebook, winit, binit, wdc1, bdc1, wdc2, bdc2, dclass);
    k_enc_attn<<<BTT, 256, 0, stream>>>(x, w1, b1, b2, w2T, wqkT, wqkv, wout, bout, hbar);
    k_enc_conv<<<dim3(8, 32), 256, 0, stream>>>(hbar, wc1T, cb1, wc2T, cb2, wproj, bproj, zbuf);
    k_vq_reduce<<<256, 256, 0, stream>>>(zbuf, codebook, accp);
    k_vq_final<<<1, 64, 0, stream>>>(accp, out, out_size);
    k_dec_gen<<<BTT, TBLK, 0, stream>>>(seeds, dclass, g1, gb1, g2, gb2, g3, gb3, out);
}

// Round 6
// 2577.083 us; speedup vs baseline: 2.4381x; 1.3140x over previous
//
#include <hip/hip_runtime.h>
#include <cstdint>
#include <cstddef>

#define NM    53
#define NMP   56
#define HD    256
#define BTT   4096

typedef __attribute__((ext_vector_type(8))) short short8v;
typedef __attribute__((ext_vector_type(4))) float f32x4;
#define MFMA16(a,b,c) __builtin_amdgcn_mfma_f32_16x16x32_bf16(a,b,c,0,0,0)

__device__ __forceinline__ float4 ldg4(const float* p) { return *(const float4*)p; }

__device__ __forceinline__ short f2bf(float f){
    union { float f; uint32_t u; } v; v.f = f;
    uint32_t r = v.u + 0x7fff + ((v.u >> 16) & 1);
    return (short)(r >> 16);
}
__device__ __forceinline__ float bf2f(short s){
    union { uint32_t u; float f; } v; v.u = ((uint32_t)(uint16_t)s) << 16;
    return v.f;
}

// ---------------- prep: bf16-transpose weights --------------------------------
// w2T[n][k]=w2[k][n] | wqkT[n][k]=wqkv[k][n] n<1024 | g1T,g2T same | g3T[16][256] pad
__global__ void k_prep_bf16(const float* __restrict__ w2, const float* __restrict__ wqkv,
                            const float* __restrict__ g1, const float* __restrict__ g2,
                            const float* __restrict__ g3,
                            short* __restrict__ w2T, short* __restrict__ wqkT,
                            short* __restrict__ g1T, short* __restrict__ g2T,
                            short* __restrict__ g3T)
{
    const int idx = blockIdx.x*256 + threadIdx.x;
    if (idx < 65536) {
        const int n = idx >> 8, k = idx & 255;
        w2T[idx] = f2bf(w2[k*HD + n]);
    } else if (idx < 327680) {
        const int j = idx - 65536;
        const int n = j >> 8, k = j & 255;
        wqkT[j] = f2bf(wqkv[(size_t)k*1536 + n]);
    } else if (idx < 393216) {
        const int j = idx - 327680;
        const int n = j >> 8, k = j & 255;
        g1T[j] = f2bf(g1[k*HD + n]);
    } else if (idx < 458752) {
        const int j = idx - 393216;
        const int n = j >> 8, k = j & 255;
        g2T[j] = f2bf(g2[k*HD + n]);
    } else if (idx < 462848) {
        const int j = idx - 458752;
        const int n = j >> 8, k = j & 255;   // n<16
        g3T[j] = (n < 3) ? f2bf(g3[k*3 + n]) : (short)0;
    }
}

// ---------------- kernel 1: encoder MLP + attention (bf16 MFMA) --------------
// 256 threads = 4 waves. One bt per block. LDS ~73 KB -> 2 blocks/CU.
__global__ __launch_bounds__(256) void k_enc_attn(
    const float* __restrict__ x,
    const float* __restrict__ w1, const float* __restrict__ b1,
    const float* __restrict__ b2,
    const short* __restrict__ w2T,   // [256][256] bf16 (row n, col k)
    const short* __restrict__ wqkT,  // [1024][256] bf16 (row n, col k)
    const float* __restrict__ wqkv,  // fp32 original (for Wv columns)
    const float* __restrict__ wout, const float* __restrict__ bout,
    float* __restrict__ hbar)
{
    const int bt   = blockIdx.x;
    const int tid  = threadIdx.x;
    const int wv   = tid >> 6;     // wave 0..3
    const int lane = tid & 63;
    const int lr   = lane & 15;    // fragment row/col index
    const int lg   = lane >> 4;    // k-group

    __shared__ __align__(16) char  sU[35840];
    __shared__ __align__(16) short sH2b[64*264];              // 33792 B
    __shared__ __align__(16) float sSmall[64+256+512];        //  3328 B
    short* sH1b = (short*)sU;                 // [64][264] bf16
    short* sQ   = (short*)sU;                 // [64][72]  bf16
    short* sK   = (short*)(sU + 9216);        // [64][72]  bf16
    float* sDots= (float*)(sU + 18432);       // [64][68]  f32
    float* sPart= (float*)sU;                 // [4][256]  f32
    float* sWj  = sSmall;
    float* sHw  = sSmall + 64;
    float* sObar= sSmall + 320;

    // ---- P1: h1 = relu(x @ w1 + b1) -> bf16 LDS (pad rows zero) ----
    {
        const float* xr = x + (size_t)bt * (NM*3);
        const float W0 = w1[tid], W1 = w1[HD+tid], W2 = w1[2*HD+tid], B = b1[tid];
        for (int t = 0; t < 64; ++t) {
            float v = 0.f;
            if (t < NM)
                v = fmaxf(fmaf(xr[t*3], W0, fmaf(xr[t*3+1], W1, fmaf(xr[t*3+2], W2, B))), 0.f);
            sH1b[t*264 + tid] = f2bf(v);
        }
    }
    __syncthreads();

    // ---- P2: h2 = relu(h1 @ w2 + b2) -> bf16 LDS, rows>=53 forced 0 ----
    {
        short8v a[8];
#pragma unroll
        for (int ks = 0; ks < 8; ++ks)
            a[ks] = *(const short8v*)(sH1b + (wv*16 + lr)*264 + ks*32 + lg*8);
        for (int nf = 0; nf < 16; ++nf) {
            f32x4 acc = {0.f, 0.f, 0.f, 0.f};
#pragma unroll
            for (int ks = 0; ks < 8; ++ks) {
                const short8v bfr = *(const short8v*)(w2T + (size_t)(nf*16 + lr)*HD + ks*32 + lg*8);
                acc = MFMA16(a[ks], bfr, acc);
            }
            const int n = nf*16 + lr;
            const float bb = b2[n];
#pragma unroll
            for (int r = 0; r < 4; ++r) {
                const int m = wv*16 + lg*4 + r;
                const float v = (m < NM) ? fmaxf(acc[r] + bb, 0.f) : 0.f;
                sH2b[m*264 + n] = f2bf(v);
            }
        }
    }
    __syncthreads();

    // preload this wave's A-strip of h2 (reused by all heads)
    short8v ah[8];
#pragma unroll
    for (int ks = 0; ks < 8; ++ks)
        ah[ks] = *(const short8v*)(sH2b + (wv*16 + lr)*264 + ks*32 + lg*8);

    for (int h = 0; h < 8; ++h) {
        // (a) q,k projection for head h; also zero wj accumulator
        if (tid < 64) sWj[tid] = 0.f;
#pragma unroll
        for (int sec = 0; sec < 2; ++sec) {
            short* dst = sec ? sK : sQ;
            const short* wb = wqkT + (size_t)(sec*512 + h*64) * HD;
            for (int nf = 0; nf < 4; ++nf) {
                f32x4 acc = {0.f, 0.f, 0.f, 0.f};
#pragma unroll
                for (int ks = 0; ks < 8; ++ks) {
                    const short8v bfr = *(const short8v*)(wb + (size_t)(nf*16 + lr)*HD + ks*32 + lg*8);
                    acc = MFMA16(ah[ks], bfr, acc);
                }
                const int d = nf*16 + lr;
#pragma unroll
                for (int r = 0; r < 4; ++r) {
                    const int m = wv*16 + lg*4 + r;
                    dst[m*72 + d] = f2bf(acc[r]);
                }
            }
        }
        __syncthreads();

        // (b) dots = 0.125 * q @ k^T
        {
            const short8v aq0 = *(const short8v*)(sQ + (wv*16 + lr)*72 + lg*8);
            const short8v aq1 = *(const short8v*)(sQ + (wv*16 + lr)*72 + 32 + lg*8);
#pragma unroll
            for (int nf = 0; nf < 4; ++nf) {
                f32x4 acc = {0.f, 0.f, 0.f, 0.f};
                const short8v bk0 = *(const short8v*)(sK + (nf*16 + lr)*72 + lg*8);
                const short8v bk1 = *(const short8v*)(sK + (nf*16 + lr)*72 + 32 + lg*8);
                acc = MFMA16(aq0, bk0, acc);
                acc = MFMA16(aq1, bk1, acc);
                const int j = nf*16 + lr;
#pragma unroll
                for (int r = 0; r < 4; ++r) {
                    const int i = wv*16 + lg*4 + r;
                    sDots[i*68 + j] = acc[r] * 0.125f;
                }
            }
        }
        __syncthreads();

        // (c1) softmax rows in 16-lane groups + wj column partials via LDS atomics
        {
            const int jl  = lane & 15;
            const int grp = wv*4 + (lane >> 4);   // 0..15
            float w0 = 0.f, w1p = 0.f, w2p = 0.f, w3p = 0.f;
#pragma unroll
            for (int rnd = 0; rnd < 4; ++rnd) {
                const int i = rnd*16 + grp;       // 0..63
                const float v0 = sDots[i*68 + jl];
                const float v1 = sDots[i*68 + jl + 16];
                const float v2 = sDots[i*68 + jl + 32];
                const float v3 = sDots[i*68 + jl + 48];
                const bool m1 = (jl+16) < NM, m2 = (jl+32) < NM, m3 = (jl+48) < NM;
                float mx = v0;
                mx = fmaxf(mx, m1 ? v1 : -3.4e38f);
                mx = fmaxf(mx, m2 ? v2 : -3.4e38f);
                mx = fmaxf(mx, m3 ? v3 : -3.4e38f);
                mx = fmaxf(mx, __shfl_xor(mx, 1, 16));
                mx = fmaxf(mx, __shfl_xor(mx, 2, 16));
                mx = fmaxf(mx, __shfl_xor(mx, 4, 16));
                mx = fmaxf(mx, __shfl_xor(mx, 8, 16));
                const float e0 = __expf(v0 - mx);
                const float e1 = m1 ? __expf(v1 - mx) : 0.f;
                const float e2 = m2 ? __expf(v2 - mx) : 0.f;
                const float e3 = m3 ? __expf(v3 - mx) : 0.f;
                float s = e0 + e1 + e2 + e3;
                s += __shfl_xor(s, 1, 16);
                s += __shfl_xor(s, 2, 16);
                s += __shfl_xor(s, 4, 16);
                s += __shfl_xor(s, 8, 16);
                if (i < NM) {
                    const float inv = 1.f / s;
                    w0 = fmaf(e0, inv, w0);
                    w1p = fmaf(e1, inv, w1p);
                    w2p = fmaf(e2, inv, w2p);
                    w3p = fmaf(e3, inv, w3p);
                }
            }
            atomicAdd(&sWj[jl],      w0);
            atomicAdd(&sWj[jl + 16], w1p);
            atomicAdd(&sWj[jl + 32], w2p);
            atomicAdd(&sWj[jl + 48], w3p);
        }
        __syncthreads();

        // (e) hw[c] = sum_j wj[j] * h2[j][c]  (all 256 threads)
        {
            float s = 0.f;
#pragma unroll 4
            for (int j = 0; j < NM; ++j) s = fmaf(sWj[j], bf2f(sH2b[j*264 + tid]), s);
            sHw[tid] = s;
        }
        __syncthreads();

        // (f) obar[h][d] = hw . Wv[:, h*64+d], 4-way c-split, in-wave reduce (no barrier)
        {
            const int dl = lane & 15;
            const int cq = lane >> 4;
            const int d  = wv*16 + dl;
            const float* wvp = wqkv + 1024 + (size_t)h*64 + d;
            float s = 0.f;
            const int c0 = cq * 64;
#pragma unroll 8
            for (int c = c0; c < c0 + 64; ++c)
                s = fmaf(sHw[c], wvp[(size_t)c*1536], s);
            s += __shfl_xor(s, 16);
            s += __shfl_xor(s, 32);
            if (cq == 0) sObar[h*64 + d] = s;
        }
    }
    __syncthreads();

    // ---- P4: hbar = (obar/53) @ wout + bout, split over 4 waves ----
    {
        const int c4 = lane << 2;
        float a0 = 0.f, a1 = 0.f, a2 = 0.f, a3 = 0.f;
        for (int m = wv*128; m < wv*128 + 128; ++m) {
            const float ob = sObar[m] * (1.f/53.f);
            const float4 w = ldg4(wout + (size_t)m*HD + c4);
            a0 = fmaf(ob, w.x, a0); a1 = fmaf(ob, w.y, a1);
            a2 = fmaf(ob, w.z, a2); a3 = fmaf(ob, w.w, a3);
        }
        sPart[wv*256 + c4 + 0] = a0;
        sPart[wv*256 + c4 + 1] = a1;
        sPart[wv*256 + c4 + 2] = a2;
        sPart[wv*256 + c4 + 3] = a3;
    }
    __syncthreads();
    hbar[(size_t)bt*HD + tid] =
        sPart[tid] + sPart[256+tid] + sPart[512+tid] + sPart[768+tid] + bout[tid];
}

// ---------------- kernel 0: conv weight transpose [O][I][3] -> [3][I][O] -----
__global__ void k_transpose_conv(const float* __restrict__ w, float* __restrict__ wT)
{
    const int idx = blockIdx.x*256 + threadIdx.x;
    if (idx < 3*HD*HD) {
        const int o = idx & 255;
        const int i = (idx >> 8) & 255;
        const int s = idx >> 16;
        wT[idx] = w[(size_t)(o*HD + i)*3 + s];
    }
}

// ---------------- kernel 2: encoder convs + projection to z ------------------
__global__ __launch_bounds__(256) void k_enc_conv(
    const float* __restrict__ hbar,
    const float* __restrict__ wc1T, const float* __restrict__ cb1,
    const float* __restrict__ wc2T, const float* __restrict__ cb2,
    const float* __restrict__ wproj, const float* __restrict__ bproj,
    float* __restrict__ z)
{
    const int b = blockIdx.y, chunk = blockIdx.x;
    const int t0 = chunk * 16;
    const int tid = threadIdx.x;
    __shared__ __align__(16) float sIn[22][HD];
    __shared__ __align__(16) float sMid[18][HD];

    for (int idx = tid; idx < 20*HD; idx += 256) {
        const int r = idx >> 8, c = idx & 255;
        const int t = t0 - 2 + r;
        sIn[r][c] = (t >= 0 && t < 128) ? hbar[(size_t)(b*128 + t)*HD + c] : 0.f;
    }
    __syncthreads();
    const int cg = tid & 63, tg = tid >> 6;
    const int c4 = cg << 2;
    {
        float acc[5][4];
#pragma unroll
        for (int r2 = 0; r2 < 5; ++r2) { acc[r2][0]=0.f; acc[r2][1]=0.f; acc[r2][2]=0.f; acc[r2][3]=0.f; }
        for (int s = 0; s < 3; ++s)
            for (int i = 0; i < HD; ++i) {
                const float4 w = ldg4(wc1T + (size_t)(s*HD + i)*HD + c4);
#pragma unroll
                for (int r2 = 0; r2 < 5; ++r2) {
                    const float v = sIn[tg*5 + r2 + s][i];
                    acc[r2][0] = fmaf(v, w.x, acc[r2][0]);
                    acc[r2][1] = fmaf(v, w.y, acc[r2][1]);
                    acc[r2][2] = fmaf(v, w.z, acc[r2][2]);
                    acc[r2][3] = fmaf(v, w.w, acc[r2][3]);
                }
            }
        const float4 bb = ldg4(cb1 + c4);
#pragma unroll
        for (int r2 = 0; r2 < 5; ++r2) {
            const int rr = tg*5 + r2;
            if (rr < 18) {
                const int tp = t0 - 1 + rr;
                float4 o; o.x=0.f; o.y=0.f; o.z=0.f; o.w=0.f;
                if (tp >= 0 && tp < 128) {
                    o.x = fmaxf(acc[r2][0] + bb.x, 0.f);
                    o.y = fmaxf(acc[r2][1] + bb.y, 0.f);
                    o.z = fmaxf(acc[r2][2] + bb.z, 0.f);
                    o.w = fmaxf(acc[r2][3] + bb.w, 0.f);
                }
                *(float4*)(&sMid[rr][c4]) = o;
            }
        }
    }
    __syncthreads();
    {
        float acc[4][4];
#pragma unroll
        for (int r2 = 0; r2 < 4; ++r2) { acc[r2][0]=0.f; acc[r2][1]=0.f; acc[r2][2]=0.f; acc[r2][3]=0.f; }
        for (int s = 0; s < 3; ++s)
            for (int i = 0; i < HD; ++i) {
                const float4 w = ldg4(wc2T + (size_t)(s*HD + i)*HD + c4);
#pragma unroll
                for (int r2 = 0; r2 < 4; ++r2) {
                    const float v = sMid[tg*4 + r2 + s][i];
                    acc[r2][0] = fmaf(v, w.x, acc[r2][0]);
                    acc[r2][1] = fmaf(v, w.y, acc[r2][1]);
                    acc[r2][2] = fmaf(v, w.z, acc[r2][2]);
                    acc[r2][3] = fmaf(v, w.w, acc[r2][3]);
                }
            }
        const float4 bb = ldg4(cb2 + c4);
#pragma unroll
        for (int r2 = 0; r2 < 4; ++r2) {
            float4 o;
            o.x = fmaxf(acc[r2][0] + bb.x, 0.f);
            o.y = fmaxf(acc[r2][1] + bb.y, 0.f);
            o.z = fmaxf(acc[r2][2] + bb.z, 0.f);
            o.w = fmaxf(acc[r2][3] + bb.w, 0.f);
            *(float4*)(&sIn[tg*4 + r2][c4]) = o;
        }
    }
    __syncthreads();
    {
        const int cgp = tid & 15, tgp = tid >> 4;
        const int l4 = cgp << 2;
        float a0 = bproj[l4+0], a1 = bproj[l4+1], a2 = bproj[l4+2], a3 = bproj[l4+3];
        for (int i = 0; i < HD; ++i) {
            const float4 w = ldg4(wproj + (size_t)i*64 + l4);
            const float v = sIn[tgp][i];
            a0 = fmaf(v, w.x, a0); a1 = fmaf(v, w.y, a1);
            a2 = fmaf(v, w.z, a2); a3 = fmaf(v, w.w, a3);
        }
        float4 o; o.x=a0; o.y=a1; o.z=a2; o.w=a3;
        *(float4*)(z + (size_t)(b*128 + t0 + tgp)*64 + l4) = o;
    }
}

// ---------------- kernel 3: VQ loss reduction --------------------------------
__global__ void k_vq_reduce(const float* __restrict__ z,
                            const float* __restrict__ codebook,
                            float* __restrict__ acc)
{
    const int tid = threadIdx.x;
    float s = 0.f;
    for (int idx = blockIdx.x*256 + tid; idx < BTT*64; idx += gridDim.x*256) {
        const float d = z[idx] - codebook[idx & 63];
        s = fmaf(d, d, s);
    }
#pragma unroll
    for (int off = 32; off > 0; off >>= 1) s += __shfl_xor(s, off);
    __shared__ float sred[4];
    if ((tid & 63) == 0) sred[tid >> 6] = s;
    __syncthreads();
    if (tid == 0) atomicAdd(acc, sred[0] + sred[1] + sred[2] + sred[3]);
}

__global__ void k_vq_final(const float* __restrict__ acc, float* __restrict__ out, int out_size)
{
    if (threadIdx.x == 0 && blockIdx.x == 0) {
        const float mse = acc[0] * (1.f / (BTT*64.f));
        out[out_size-2] = 1.25f * mse;
        out[out_size-1] = 1.0f;
    }
}

// ---------------- kernel 4: decoder constant path (5 t-classes) --------------
__global__ __launch_bounds__(256) void k_dec_prefix(
    const float* __restrict__ codebook,
    const float* __restrict__ winit, const float* __restrict__ binit,
    const float* __restrict__ wdc1, const float* __restrict__ bdc1,
    const float* __restrict__ wdc2, const float* __restrict__ bdc2,
    float* __restrict__ dclass)
{
    const int c = threadIdx.x;
    __shared__ float sD[HD];
    __shared__ float sY1[3][HD];
    float v = binit[c];
    for (int l = 0; l < 64; ++l) v = fmaf(codebook[l], winit[l*HD + c], v);
    sD[c] = v;
    __syncthreads();
    float A0 = 0.f, A1 = 0.f, A2 = 0.f;
    for (int i = 0; i < HD; ++i) {
        const float di = sD[i];
        const float* wp = wdc1 + (size_t)c*768 + i*3;
        A0 = fmaf(wp[0], di, A0);
        A1 = fmaf(wp[1], di, A1);
        A2 = fmaf(wp[2], di, A2);
    }
    const float bb = bdc1[c];
    sY1[0][c] = fmaxf(bb + A1 + A2, 0.f);
    sY1[1][c] = fmaxf(bb + A0 + A1 + A2, 0.f);
    sY1[2][c] = fmaxf(bb + A0 + A1, 0.f);
    __syncthreads();
    const int Ls[5] = {-1, 0, 1, 1, 1};
    const int Cs[5] = { 0, 1, 1, 1, 2};
    const int Rs[5] = { 1, 1, 1, 2,-1};
    for (int cls = 0; cls < 5; ++cls) {
        float s = bdc2[c];
        const int li = Ls[cls], ci = Cs[cls], ri = Rs[cls];
        for (int i = 0; i < HD; ++i) {
            const float* wp = wdc2 + (size_t)c*768 + i*3;
            const float Lv = (li >= 0) ? sY1[li][i] : 0.f;
            const float Cv = sY1[ci][i];
            const float Rv = (ri >= 0) ? sY1[ri][i] : 0.f;
            s = fmaf(wp[0], Lv, s);
            s = fmaf(wp[1], Cv, s);
            s = fmaf(wp[2], Rv, s);
        }
        dclass[cls*HD + c] = fmaxf(s, 0.f);
    }
}

// ---------------- kernel 5: decoder generator (bf16 MFMA) --------------------
// 256 threads = 4 waves, one bt per block. LDS 2x[64][264] bf16 = 67.6 KB.
__global__ __launch_bounds__(256) void k_dec_gen(
    const float* __restrict__ seeds,
    const float* __restrict__ dclass,
    const short* __restrict__ g1T, const float* __restrict__ gb1,
    const short* __restrict__ g2T, const float* __restrict__ gb2,
    const short* __restrict__ g3T, const float* __restrict__ gb3,
    float* __restrict__ out)
{
    const int bt   = blockIdx.x;
    const int tid  = threadIdx.x;
    const int wv   = tid >> 6;
    const int lane = tid & 63;
    const int lr   = lane & 15;
    const int lg   = lane >> 4;
    const int t    = bt & 127;
    const int cls  = (t == 0) ? 0 : (t == 1) ? 1 : (t < 126) ? 2 : (t == 126) ? 3 : 4;

    __shared__ __align__(16) short sA[64*264];
    __shared__ __align__(16) short sB[64*264];

    // ---- stage: sA[t][c] = bf16(seeds[t][c] + dclass[cls][c]), pad rows 0 ----
    {
        const int cg = tid & 63, tg = tid >> 6;
        const int c4 = cg << 2;
        const float4 dv = ldg4(dclass + cls*HD + c4);
        const float* srow = seeds + (size_t)bt * (NM*HD);
        for (int it = 0; it < 16; ++it) {
            const int tt = it*4 + tg;
            short v0 = 0, v1 = 0, v2 = 0, v3 = 0;
            if (tt < NM) {
                const float4 s4 = ldg4(srow + (size_t)tt*HD + c4);
                v0 = f2bf(s4.x + dv.x); v1 = f2bf(s4.y + dv.y);
                v2 = f2bf(s4.z + dv.z); v3 = f2bf(s4.w + dv.w);
            }
            short* p = sA + tt*264 + c4;
            p[0] = v0; p[1] = v1; p[2] = v2; p[3] = v3;
        }
    }
    __syncthreads();

    // ---- GEMM1: sB = relu(sA @ g1 + gb1) ----
    {
        short8v a[8];
#pragma unroll
        for (int ks = 0; ks < 8; ++ks)
            a[ks] = *(const short8v*)(sA + (wv*16 + lr)*264 + ks*32 + lg*8);
        for (int nf = 0; nf < 16; ++nf) {
            f32x4 acc = {0.f, 0.f, 0.f, 0.f};
#pragma unroll
            for (int ks = 0; ks < 8; ++ks) {
                const short8v bfr = *(const short8v*)(g1T + (size_t)(nf*16 + lr)*HD + ks*32 + lg*8);
                acc = MFMA16(a[ks], bfr, acc);
            }
            const int n = nf*16 + lr;
            const float bb = gb1[n];
#pragma unroll
            for (int r = 0; r < 4; ++r) {
                const int m = wv*16 + lg*4 + r;
                const float v = (m < NM) ? fmaxf(acc[r] + bb, 0.f) : 0.f;
                sB[m*264 + n] = f2bf(v);
            }
        }
    }
    __syncthreads();

    // ---- GEMM2: sA = relu(sB @ g2 + gb2) ----
    {
        short8v a[8];
#pragma unroll
        for (int ks = 0; ks < 8; ++ks)
            a[ks] = *(const short8v*)(sB + (wv*16 + lr)*264 + ks*32 + lg*8);
        for (int nf = 0; nf < 16; ++nf) {
            f32x4 acc = {0.f, 0.f, 0.f, 0.f};
#pragma unroll
            for (int ks = 0; ks < 8; ++ks) {
                const short8v bfr = *(const short8v*)(g2T + (size_t)(nf*16 + lr)*HD + ks*32 + lg*8);
                acc = MFMA16(a[ks], bfr, acc);
            }
            const int n = nf*16 + lr;
            const float bb = gb2[n];
#pragma unroll
            for (int r = 0; r < 4; ++r) {
                const int m = wv*16 + lg*4 + r;
                const float v = (m < NM) ? fmaxf(acc[r] + bb, 0.f) : 0.f;
                sA[m*264 + n] = f2bf(v);
            }
        }
    }
    __syncthreads();

    // ---- GEMM3: out = sA @ g3 + gb3  (n = 0..2 valid of 16) ----
    {
        f32x4 acc = {0.f, 0.f, 0.f, 0.f};
#pragma unroll
        for (int ks = 0; ks < 8; ++ks) {
            const short8v a = *(const short8v*)(sA + (wv*16 + lr)*264 + ks*32 + lg*8);
            const short8v bfr = *(const short8v*)(g3T + (size_t)lr*HD + ks*32 + lg*8);
            acc = MFMA16(a, bfr, acc);
        }
        if (lr < 3) {
            const float bb = gb3[lr];
#pragma unroll
            for (int r = 0; r < 4; ++r) {
                const int m = wv*16 + lg*4 + r;
                if (m < NM)
                    out[(size_t)(bt*NM + m)*3 + lr] = acc[r] + bb;
            }
        }
    }
}

// ---------------------------------------------------------------------------
extern "C" void kernel_launch(void* const* d_in, const int* in_sizes, int n_in,
                              void* d_out, int out_size, void* d_ws, size_t ws_size,
                              hipStream_t stream)
{
    const float* x      = (const float*)d_in[0];
    const float* seeds  = (const float*)d_in[1];
    const float* w1     = (const float*)d_in[2];
    const float* b1     = (const float*)d_in[3];
    const float* w2     = (const float*)d_in[4];
    const float* b2     = (const float*)d_in[5];
    const float* wqkv   = (const float*)d_in[6];
    const float* wout   = (const float*)d_in[7];
    const float* bout   = (const float*)d_in[8];
    const float* wc1    = (const float*)d_in[9];
    const float* cb1    = (const float*)d_in[10];
    const float* wc2    = (const float*)d_in[11];
    const float* cb2    = (const float*)d_in[12];
    const float* wproj  = (const float*)d_in[13];
    const float* bproj  = (const float*)d_in[14];
    const float* codebook = (const float*)d_in[15];
    const float* winit  = (const float*)d_in[16];
    const float* binit  = (const float*)d_in[17];
    const float* wdc1   = (const float*)d_in[18];
    const float* bdc1   = (const float*)d_in[19];
    const float* wdc2   = (const float*)d_in[20];
    const float* bdc2   = (const float*)d_in[21];
    const float* g1     = (const float*)d_in[22];
    const float* gb1    = (const float*)d_in[23];
    const float* g2     = (const float*)d_in[24];
    const float* gb2    = (const float*)d_in[25];
    const float* g3     = (const float*)d_in[26];
    const float* gb3    = (const float*)d_in[27];

    float* ws     = (float*)d_ws;
    float* hbar   = ws;                    // 1,048,576 f
    float* zbuf   = ws + 1048576;          //   262,144 f
    float* wc1T   = ws + 1310720;          //   196,608 f
    float* wc2T   = ws + 1507328;          //   196,608 f
    float* dclass = ws + 1703936;          //     1,280 f
    float* accp   = ws + 1705216;          //         4 f
    short* w2T    = (short*)(ws + 1705220);   //  65,536 bf16
    short* wqkT   = (short*)(ws + 1737988);   // 262,144 bf16
    short* g1T    = (short*)(ws + 1869060);   //  65,536 bf16
    short* g2T    = (short*)(ws + 1901828);   //  65,536 bf16
    short* g3T    = (short*)(ws + 1934596);   //   4,096 bf16
    // end ~1,936,644 floats = 7.75 MB

    float* out = (float*)d_out;

    hipMemsetAsync(accp, 0, sizeof(float), stream);
    k_prep_bf16<<<1808, 256, 0, stream>>>(w2, wqkv, g1, g2, g3, w2T, wqkT, g1T, g2T, g3T);
    k_transpose_conv<<<768, 256, 0, stream>>>(wc1, wc1T);
    k_transpose_conv<<<768, 256, 0, stream>>>(wc2, wc2T);
    k_dec_prefix<<<1, 256, 0, stream>>>(codebook, winit, binit, wdc1, bdc1, wdc2, bdc2, dclass);
    k_enc_attn<<<BTT, 256, 0, stream>>>(x, w1, b1, b2, w2T, wqkT, wqkv, wout, bout, hbar);
    k_enc_conv<<<dim3(8, 32), 256, 0, stream>>>(hbar, wc1T, cb1, wc2T, cb2, wproj, bproj, zbuf);
    k_vq_reduce<<<256, 256, 0, stream>>>(zbuf, codebook, accp);
    k_vq_final<<<1, 64, 0, stream>>>(accp, out, out_size);
    k_dec_gen<<<BTT, 256, 0, stream>>>(seeds, dclass, g1T, gb1, g2T, gb2, g3T, gb3, out);
}

// Round 7
// 2437.611 us; speedup vs baseline: 2.5776x; 1.0572x over previous
//
#include <hip/hip_runtime.h>
#include <cstdint>
#include <cstddef>

#define NM    53
#define NMP   56
#define HD    256
#define BTT   4096

typedef __attribute__((ext_vector_type(8))) short short8v;
typedef __attribute__((ext_vector_type(4))) float f32x4;
#define MFMA16(a,b,c) __builtin_amdgcn_mfma_f32_16x16x32_bf16(a,b,c,0,0,0)

__device__ __forceinline__ float4 ldg4(const float* p) { return *(const float4*)p; }

__device__ __forceinline__ short f2bf(float f){
    union { float f; uint32_t u; } v; v.f = f;
    uint32_t r = v.u + 0x7fff + ((v.u >> 16) & 1);
    return (short)(r >> 16);
}
__device__ __forceinline__ float bf2f(short s){
    union { uint32_t u; float f; } v; v.u = ((uint32_t)(uint16_t)s) << 16;
    return v.f;
}

// ---------------- prep: bf16-transpose weights --------------------------------
__global__ void k_prep_bf16(const float* __restrict__ w2, const float* __restrict__ wqkv,
                            const float* __restrict__ g1, const float* __restrict__ g2,
                            const float* __restrict__ g3,
                            short* __restrict__ w2T, short* __restrict__ wqkT,
                            short* __restrict__ g1T, short* __restrict__ g2T,
                            short* __restrict__ g3T)
{
    const int idx = blockIdx.x*256 + threadIdx.x;
    if (idx < 65536) {
        const int n = idx >> 8, k = idx & 255;
        w2T[idx] = f2bf(w2[k*HD + n]);
    } else if (idx < 327680) {
        const int j = idx - 65536;
        const int n = j >> 8, k = j & 255;
        wqkT[j] = f2bf(wqkv[(size_t)k*1536 + n]);
    } else if (idx < 393216) {
        const int j = idx - 327680;
        const int n = j >> 8, k = j & 255;
        g1T[j] = f2bf(g1[k*HD + n]);
    } else if (idx < 458752) {
        const int j = idx - 393216;
        const int n = j >> 8, k = j & 255;
        g2T[j] = f2bf(g2[k*HD + n]);
    } else if (idx < 462848) {
        const int j = idx - 458752;
        const int n = j >> 8, k = j & 255;   // n<16
        g3T[j] = (n < 3) ? f2bf(g3[k*3 + n]) : (short)0;
    }
}

// ---------------- kernel 1: encoder MLP + attention (bf16 MFMA) --------------
// 256 threads = 4 waves. One bt per block. LDS ~78 KB -> 2 blocks/CU.
// Head loop: 1 barrier/head (double-buffered K, register softmax, wj atomics).
__global__ __launch_bounds__(256) void k_enc_attn(
    const float* __restrict__ x,
    const float* __restrict__ w1, const float* __restrict__ b1,
    const float* __restrict__ b2,
    const short* __restrict__ w2T,   // [256][256] bf16 (row n, col k)
    const short* __restrict__ wqkT,  // [1024][256] bf16 (row n, col k)
    const float* __restrict__ wqkv,  // fp32 original (for Wv columns)
    const float* __restrict__ wout, const float* __restrict__ bout,
    float* __restrict__ hbar)
{
    const int bt   = blockIdx.x;
    const int tid  = threadIdx.x;
    const int wv   = tid >> 6;     // wave 0..3
    const int lane = tid & 63;
    const int lr   = lane & 15;    // fragment row/col index
    const int lg   = lane >> 4;    // k-group

    __shared__ __align__(16) char  sU[33792];      // h1 / {Q 9216 + K dbuf 18432} / part 4096
    __shared__ __align__(16) short sH2b[64*264];   // 33792 B
    __shared__ __align__(16) float sWjAll[64*8];   //  2048 B  [j][h]
    __shared__ __align__(16) float sHwAll[8*256];  //  8192 B  [h][c]
    __shared__ __align__(16) float sObar[512];     //  2048 B
    short* sH1b = (short*)sU;                 // [64][264] bf16
    short* sQ   = (short*)sU;                 // [64][72]  bf16
    short* sK0  = (short*)(sU + 9216);        // [64][72]  bf16
    short* sK1  = (short*)(sU + 18432);       // [64][72]  bf16
    float* sPart= (float*)sU;                 // [4][256]  f32

    // ---- P1: h1 = relu(x @ w1 + b1) -> bf16 LDS (pad rows zero) ----
    {
        const float* xr = x + (size_t)bt * (NM*3);
        const float W0 = w1[tid], W1 = w1[HD+tid], W2 = w1[2*HD+tid], B = b1[tid];
        for (int t = 0; t < 64; ++t) {
            float v = 0.f;
            if (t < NM)
                v = fmaxf(fmaf(xr[t*3], W0, fmaf(xr[t*3+1], W1, fmaf(xr[t*3+2], W2, B))), 0.f);
            sH1b[t*264 + tid] = f2bf(v);
        }
        // zero the wj accumulator (protected by head-0's (a) barrier)
        sWjAll[tid] = 0.f;
        sWjAll[256 + tid] = 0.f;
    }
    __syncthreads();

    // ---- P2: h2 = relu(h1 @ w2 + b2) -> bf16 LDS, rows>=53 forced 0 ----
    {
        short8v a[8];
#pragma unroll
        for (int ks = 0; ks < 8; ++ks)
            a[ks] = *(const short8v*)(sH1b + (wv*16 + lr)*264 + ks*32 + lg*8);
        for (int nf = 0; nf < 16; ++nf) {
            f32x4 acc = {0.f, 0.f, 0.f, 0.f};
#pragma unroll
            for (int ks = 0; ks < 8; ++ks) {
                const short8v bfr = *(const short8v*)(w2T + (size_t)(nf*16 + lr)*HD + ks*32 + lg*8);
                acc = MFMA16(a[ks], bfr, acc);
            }
            const int n = nf*16 + lr;
            const float bb = b2[n];
#pragma unroll
            for (int r = 0; r < 4; ++r) {
                const int m = wv*16 + lg*4 + r;
                const float v = (m < NM) ? fmaxf(acc[r] + bb, 0.f) : 0.f;
                sH2b[m*264 + n] = f2bf(v);
            }
        }
    }
    __syncthreads();

    // preload this wave's A-strip of h2 (reused by all heads)
    short8v ah[8];
#pragma unroll
    for (int ks = 0; ks < 8; ++ks)
        ah[ks] = *(const short8v*)(sH2b + (wv*16 + lr)*264 + ks*32 + lg*8);

    for (int h = 0; h < 8; ++h) {
        short* kb = (h & 1) ? sK1 : sK0;
        // (a) q,k projection for head h (pad rows stay 0 since h2 pad rows are 0)
#pragma unroll
        for (int sec = 0; sec < 2; ++sec) {
            short* dst = sec ? kb : sQ;
            const short* wb = wqkT + (size_t)(sec*512 + h*64) * HD;
            for (int nf = 0; nf < 4; ++nf) {
                f32x4 acc = {0.f, 0.f, 0.f, 0.f};
#pragma unroll
                for (int ks = 0; ks < 8; ++ks) {
                    const short8v bfr = *(const short8v*)(wb + (size_t)(nf*16 + lr)*HD + ks*32 + lg*8);
                    acc = MFMA16(ah[ks], bfr, acc);
                }
                const int d = nf*16 + lr;
#pragma unroll
                for (int r = 0; r < 4; ++r) {
                    const int m = wv*16 + lg*4 + r;
                    dst[m*72 + d] = f2bf(acc[r]);
                }
            }
        }
        __syncthreads();   // the only barrier in the head loop

        // (b) dots + softmax + wj, fully in registers.
        // Lane holds p[r][nf]: row i=wv*16+lg*4+r, col j=nf*16+lr.
        // No max-subtraction: |dots| ~1e-5 (0.02-scale weights), exp overflow
        // needs |x|>88 -- 7 orders of margin. Identical softmax value.
        {
            const short8v aq0 = *(const short8v*)(sQ + (wv*16 + lr)*72 + lg*8);
            const short8v aq1 = *(const short8v*)(sQ + (wv*16 + lr)*72 + 32 + lg*8);
            f32x4 pr[4];
#pragma unroll
            for (int nf = 0; nf < 4; ++nf) {
                f32x4 acc = {0.f, 0.f, 0.f, 0.f};
                const short8v bk0 = *(const short8v*)(kb + (nf*16 + lr)*72 + lg*8);
                const short8v bk1 = *(const short8v*)(kb + (nf*16 + lr)*72 + 32 + lg*8);
                acc = MFMA16(aq0, bk0, acc);
                acc = MFMA16(aq1, bk1, acc);
                pr[nf] = acc;
            }
            float e[4][4];   // [r][nf]
#pragma unroll
            for (int nf = 0; nf < 4; ++nf) {
                const bool jok = (nf < 3) || (lr < 5);   // j = nf*16+lr < 53
#pragma unroll
                for (int r = 0; r < 4; ++r)
                    e[r][nf] = jok ? __expf(pr[nf][r] * 0.125f) : 0.f;
            }
            float inv[4];
#pragma unroll
            for (int r = 0; r < 4; ++r) {
                float s = (e[r][0] + e[r][1]) + (e[r][2] + e[r][3]);
                s += __shfl_xor(s, 1, 16);
                s += __shfl_xor(s, 2, 16);
                s += __shfl_xor(s, 4, 16);
                s += __shfl_xor(s, 8, 16);
                inv[r] = 1.0f / s;
            }
#pragma unroll
            for (int nf = 0; nf < 4; ++nf) {
                float w = 0.f;
#pragma unroll
                for (int r = 0; r < 4; ++r) {
                    const int i = wv*16 + lg*4 + r;
                    if (i < NM) w = fmaf(e[r][nf], inv[r], w);
                }
                w += __shfl_xor(w, 16);
                w += __shfl_xor(w, 32);
                if (lg == 0) atomicAdd(&sWjAll[(nf*16 + lr)*8 + h], w);
            }
        }
        // no end-of-head barrier: next (a) writes sQ (own rows) and the OTHER
        // K buffer; hazard window is 2 heads, covered by the next (a) barrier.
    }
    __syncthreads();   // all heads' wj atomics complete

    // ---- (e) batched: hw[h][c] = sum_j wj[j][h] * h2[j][c], c = tid ----
    {
        float hw[8] = {0.f,0.f,0.f,0.f,0.f,0.f,0.f,0.f};
        for (int j = 0; j < NM; ++j) {
            const float hv = bf2f(sH2b[j*264 + tid]);
            const float4 wj0 = *(const float4*)&sWjAll[j*8];
            const float4 wj1 = *(const float4*)&sWjAll[j*8 + 4];
            hw[0] = fmaf(wj0.x, hv, hw[0]); hw[1] = fmaf(wj0.y, hv, hw[1]);
            hw[2] = fmaf(wj0.z, hv, hw[2]); hw[3] = fmaf(wj0.w, hv, hw[3]);
            hw[4] = fmaf(wj1.x, hv, hw[4]); hw[5] = fmaf(wj1.y, hv, hw[5]);
            hw[6] = fmaf(wj1.z, hv, hw[6]); hw[7] = fmaf(wj1.w, hv, hw[7]);
        }
#pragma unroll
        for (int h = 0; h < 8; ++h) sHwAll[h*256 + tid] = hw[h];
    }
    __syncthreads();

    // ---- (f) batched: obar[o] = sum_c hw[o>>6][c] * wqkv[c][1024+o], o=tid,tid+256
    {
        const int h1 = tid >> 6;          // 0..3
        const float* base = wqkv + 1024;
        float a0 = 0.f, a1 = 0.f;
        for (int c = 0; c < HD; ++c) {
            const float* rowp = base + (size_t)c*1536;
            a0 = fmaf(sHwAll[h1*256 + c],       rowp[tid],       a0);
            a1 = fmaf(sHwAll[1024 + h1*256 + c], rowp[256 + tid], a1);
        }
        sObar[tid] = a0;
        sObar[256 + tid] = a1;
    }
    __syncthreads();

    // ---- P4: hbar = (obar/53) @ wout + bout, split over 4 waves ----
    {
        const int c4 = lane << 2;
        float a0 = 0.f, a1 = 0.f, a2 = 0.f, a3 = 0.f;
        for (int m = wv*128; m < wv*128 + 128; ++m) {
            const float ob = sObar[m] * (1.f/53.f);
            const float4 w = ldg4(wout + (size_t)m*HD + c4);
            a0 = fmaf(ob, w.x, a0); a1 = fmaf(ob, w.y, a1);
            a2 = fmaf(ob, w.z, a2); a3 = fmaf(ob, w.w, a3);
        }
        sPart[wv*256 + c4 + 0] = a0;
        sPart[wv*256 + c4 + 1] = a1;
        sPart[wv*256 + c4 + 2] = a2;
        sPart[wv*256 + c4 + 3] = a3;
    }
    __syncthreads();
    hbar[(size_t)bt*HD + tid] =
        sPart[tid] + sPart[256+tid] + sPart[512+tid] + sPart[768+tid] + bout[tid];
}

// ---------------- kernel 0: conv weight transpose [O][I][3] -> [3][I][O] -----
__global__ void k_transpose_conv(const float* __restrict__ w, float* __restrict__ wT)
{
    const int idx = blockIdx.x*256 + threadIdx.x;
    if (idx < 3*HD*HD) {
        const int o = idx & 255;
        const int i = (idx >> 8) & 255;
        const int s = idx >> 16;
        wT[idx] = w[(size_t)(o*HD + i)*3 + s];
    }
}

// ---------------- kernel 2: encoder convs + projection to z ------------------
__global__ __launch_bounds__(256) void k_enc_conv(
    const float* __restrict__ hbar,
    const float* __restrict__ wc1T, const float* __restrict__ cb1,
    const float* __restrict__ wc2T, const float* __restrict__ cb2,
    const float* __restrict__ wproj, const float* __restrict__ bproj,
    float* __restrict__ z)
{
    const int b = blockIdx.y, chunk = blockIdx.x;
    const int t0 = chunk * 16;
    const int tid = threadIdx.x;
    __shared__ __align__(16) float sIn[22][HD];
    __shared__ __align__(16) float sMid[18][HD];

    for (int idx = tid; idx < 20*HD; idx += 256) {
        const int r = idx >> 8, c = idx & 255;
        const int t = t0 - 2 + r;
        sIn[r][c] = (t >= 0 && t < 128) ? hbar[(size_t)(b*128 + t)*HD + c] : 0.f;
    }
    __syncthreads();
    const int cg = tid & 63, tg = tid >> 6;
    const int c4 = cg << 2;
    {
        float acc[5][4];
#pragma unroll
        for (int r2 = 0; r2 < 5; ++r2) { acc[r2][0]=0.f; acc[r2][1]=0.f; acc[r2][2]=0.f; acc[r2][3]=0.f; }
        for (int s = 0; s < 3; ++s)
            for (int i = 0; i < HD; ++i) {
                const float4 w = ldg4(wc1T + (size_t)(s*HD + i)*HD + c4);
#pragma unroll
                for (int r2 = 0; r2 < 5; ++r2) {
                    const float v = sIn[tg*5 + r2 + s][i];
                    acc[r2][0] = fmaf(v, w.x, acc[r2][0]);
                    acc[r2][1] = fmaf(v, w.y, acc[r2][1]);
                    acc[r2][2] = fmaf(v, w.z, acc[r2][2]);
                    acc[r2][3] = fmaf(v, w.w, acc[r2][3]);
                }
            }
        const float4 bb = ldg4(cb1 + c4);
#pragma unroll
        for (int r2 = 0; r2 < 5; ++r2) {
            const int rr = tg*5 + r2;
            if (rr < 18) {
                const int tp = t0 - 1 + rr;
                float4 o; o.x=0.f; o.y=0.f; o.z=0.f; o.w=0.f;
                if (tp >= 0 && tp < 128) {
                    o.x = fmaxf(acc[r2][0] + bb.x, 0.f);
                    o.y = fmaxf(acc[r2][1] + bb.y, 0.f);
                    o.z = fmaxf(acc[r2][2] + bb.z, 0.f);
                    o.w = fmaxf(acc[r2][3] + bb.w, 0.f);
                }
                *(float4*)(&sMid[rr][c4]) = o;
            }
        }
    }
    __syncthreads();
    {
        float acc[4][4];
#pragma unroll
        for (int r2 = 0; r2 < 4; ++r2) { acc[r2][0]=0.f; acc[r2][1]=0.f; acc[r2][2]=0.f; acc[r2][3]=0.f; }
        for (int s = 0; s < 3; ++s)
            for (int i = 0; i < HD; ++i) {
                const float4 w = ldg4(wc2T + (size_t)(s*HD + i)*HD + c4);
#pragma unroll
                for (int r2 = 0; r2 < 4; ++r2) {
                    const float v = sMid[tg*4 + r2 + s][i];
                    acc[r2][0] = fmaf(v, w.x, acc[r2][0]);
                    acc[r2][1] = fmaf(v, w.y, acc[r2][1]);
                    acc[r2][2] = fmaf(v, w.z, acc[r2][2]);
                    acc[r2][3] = fmaf(v, w.w, acc[r2][3]);
                }
            }
        const float4 bb = ldg4(cb2 + c4);
#pragma unroll
        for (int r2 = 0; r2 < 4; ++r2) {
            float4 o;
            o.x = fmaxf(acc[r2][0] + bb.x, 0.f);
            o.y = fmaxf(acc[r2][1] + bb.y, 0.f);
            o.z = fmaxf(acc[r2][2] + bb.z, 0.f);
            o.w = fmaxf(acc[r2][3] + bb.w, 0.f);
            *(float4*)(&sIn[tg*4 + r2][c4]) = o;
        }
    }
    __syncthreads();
    {
        const int cgp = tid & 15, tgp = tid >> 4;
        const int l4 = cgp << 2;
        float a0 = bproj[l4+0], a1 = bproj[l4+1], a2 = bproj[l4+2], a3 = bproj[l4+3];
        for (int i = 0; i < HD; ++i) {
            const float4 w = ldg4(wproj + (size_t)i*64 + l4);
            const float v = sIn[tgp][i];
            a0 = fmaf(v, w.x, a0); a1 = fmaf(v, w.y, a1);
            a2 = fmaf(v, w.z, a2); a3 = fmaf(v, w.w, a3);
        }
        float4 o; o.x=a0; o.y=a1; o.z=a2; o.w=a3;
        *(float4*)(z + (size_t)(b*128 + t0 + tgp)*64 + l4) = o;
    }
}

// ---------------- kernel 3: VQ loss reduction --------------------------------
__global__ void k_vq_reduce(const float* __restrict__ z,
                            const float* __restrict__ codebook,
                            float* __restrict__ acc)
{
    const int tid = threadIdx.x;
    float s = 0.f;
    for (int idx = blockIdx.x*256 + tid; idx < BTT*64; idx += gridDim.x*256) {
        const float d = z[idx] - codebook[idx & 63];
        s = fmaf(d, d, s);
    }
#pragma unroll
    for (int off = 32; off > 0; off >>= 1) s += __shfl_xor(s, off);
    __shared__ float sred[4];
    if ((tid & 63) == 0) sred[tid >> 6] = s;
    __syncthreads();
    if (tid == 0) atomicAdd(acc, sred[0] + sred[1] + sred[2] + sred[3]);
}

__global__ void k_vq_final(const float* __restrict__ acc, float* __restrict__ out, int out_size)
{
    if (threadIdx.x == 0 && blockIdx.x == 0) {
        const float mse = acc[0] * (1.f / (BTT*64.f));
        out[out_size-2] = 1.25f * mse;
        out[out_size-1] = 1.0f;
    }
}

// ---------------- kernel 4: decoder constant path (5 t-classes) --------------
__global__ __launch_bounds__(256) void k_dec_prefix(
    const float* __restrict__ codebook,
    const float* __restrict__ winit, const float* __restrict__ binit,
    const float* __restrict__ wdc1, const float* __restrict__ bdc1,
    const float* __restrict__ wdc2, const float* __restrict__ bdc2,
    float* __restrict__ dclass)
{
    const int c = threadIdx.x;
    __shared__ float sD[HD];
    __shared__ float sY1[3][HD];
    float v = binit[c];
    for (int l = 0; l < 64; ++l) v = fmaf(codebook[l], winit[l*HD + c], v);
    sD[c] = v;
    __syncthreads();
    float A0 = 0.f, A1 = 0.f, A2 = 0.f;
    for (int i = 0; i < HD; ++i) {
        const float di = sD[i];
        const float* wp = wdc1 + (size_t)c*768 + i*3;
        A0 = fmaf(wp[0], di, A0);
        A1 = fmaf(wp[1], di, A1);
        A2 = fmaf(wp[2], di, A2);
    }
    const float bb = bdc1[c];
    sY1[0][c] = fmaxf(bb + A1 + A2, 0.f);
    sY1[1][c] = fmaxf(bb + A0 + A1 + A2, 0.f);
    sY1[2][c] = fmaxf(bb + A0 + A1, 0.f);
    __syncthreads();
    const int Ls[5] = {-1, 0, 1, 1, 1};
    const int Cs[5] = { 0, 1, 1, 1, 2};
    const int Rs[5] = { 1, 1, 1, 2,-1};
    for (int cls = 0; cls < 5; ++cls) {
        float s = bdc2[c];
        const int li = Ls[cls], ci = Cs[cls], ri = Rs[cls];
        for (int i = 0; i < HD; ++i) {
            const float* wp = wdc2 + (size_t)c*768 + i*3;
            const float Lv = (li >= 0) ? sY1[li][i] : 0.f;
            const float Cv = sY1[ci][i];
            const float Rv = (ri >= 0) ? sY1[ri][i] : 0.f;
            s = fmaf(wp[0], Lv, s);
            s = fmaf(wp[1], Cv, s);
            s = fmaf(wp[2], Rv, s);
        }
        dclass[cls*HD + c] = fmaxf(s, 0.f);
    }
}

// ---------------- kernel 5: decoder generator (bf16 MFMA) --------------------
__global__ __launch_bounds__(256) void k_dec_gen(
    const float* __restrict__ seeds,
    const float* __restrict__ dclass,
    const short* __restrict__ g1T, const float* __restrict__ gb1,
    const short* __restrict__ g2T, const float* __restrict__ gb2,
    const short* __restrict__ g3T, const float* __restrict__ gb3,
    float* __restrict__ out)
{
    const int bt   = blockIdx.x;
    const int tid  = threadIdx.x;
    const int wv   = tid >> 6;
    const int lane = tid & 63;
    const int lr   = lane & 15;
    const int lg   = lane >> 4;
    const int t    = bt & 127;
    const int cls  = (t == 0) ? 0 : (t == 1) ? 1 : (t < 126) ? 2 : (t == 126) ? 3 : 4;

    __shared__ __align__(16) short sA[64*264];
    __shared__ __align__(16) short sB[64*264];

    {
        const int cg = tid & 63, tg = tid >> 6;
        const int c4 = cg << 2;
        const float4 dv = ldg4(dclass + cls*HD + c4);
        const float* srow = seeds + (size_t)bt * (NM*HD);
        for (int it = 0; it < 16; ++it) {
            const int tt = it*4 + tg;
            short v0 = 0, v1 = 0, v2 = 0, v3 = 0;
            if (tt < NM) {
                const float4 s4 = ldg4(srow + (size_t)tt*HD + c4);
                v0 = f2bf(s4.x + dv.x); v1 = f2bf(s4.y + dv.y);
                v2 = f2bf(s4.z + dv.z); v3 = f2bf(s4.w + dv.w);
            }
            short* p = sA + tt*264 + c4;
            p[0] = v0; p[1] = v1; p[2] = v2; p[3] = v3;
        }
    }
    __syncthreads();

    {
        short8v a[8];
#pragma unroll
        for (int ks = 0; ks < 8; ++ks)
            a[ks] = *(const short8v*)(sA + (wv*16 + lr)*264 + ks*32 + lg*8);
        for (int nf = 0; nf < 16; ++nf) {
            f32x4 acc = {0.f, 0.f, 0.f, 0.f};
#pragma unroll
            for (int ks = 0; ks < 8; ++ks) {
                const short8v bfr = *(const short8v*)(g1T + (size_t)(nf*16 + lr)*HD + ks*32 + lg*8);
                acc = MFMA16(a[ks], bfr, acc);
            }
            const int n = nf*16 + lr;
            const float bb = gb1[n];
#pragma unroll
            for (int r = 0; r < 4; ++r) {
                const int m = wv*16 + lg*4 + r;
                const float v = (m < NM) ? fmaxf(acc[r] + bb, 0.f) : 0.f;
                sB[m*264 + n] = f2bf(v);
            }
        }
    }
    __syncthreads();

    {
        short8v a[8];
#pragma unroll
        for (int ks = 0; ks < 8; ++ks)
            a[ks] = *(const short8v*)(sB + (wv*16 + lr)*264 + ks*32 + lg*8);
        for (int nf = 0; nf < 16; ++nf) {
            f32x4 acc = {0.f, 0.f, 0.f, 0.f};
#pragma unroll
            for (int ks = 0; ks < 8; ++ks) {
                const short8v bfr = *(const short8v*)(g2T + (size_t)(nf*16 + lr)*HD + ks*32 + lg*8);
                acc = MFMA16(a[ks], bfr, acc);
            }
            const int n = nf*16 + lr;
            const float bb = gb2[n];
#pragma unroll
            for (int r = 0; r < 4; ++r) {
                const int m = wv*16 + lg*4 + r;
                const float v = (m < NM) ? fmaxf(acc[r] + bb, 0.f) : 0.f;
                sA[m*264 + n] = f2bf(v);
            }
        }
    }
    __syncthreads();

    {
        f32x4 acc = {0.f, 0.f, 0.f, 0.f};
#pragma unroll
        for (int ks = 0; ks < 8; ++ks) {
            const short8v a = *(const short8v*)(sA + (wv*16 + lr)*264 + ks*32 + lg*8);
            const short8v bfr = *(const short8v*)(g3T + (size_t)lr*HD + ks*32 + lg*8);
            acc = MFMA16(a, bfr, acc);
        }
        if (lr < 3) {
            const float bb = gb3[lr];
#pragma unroll
            for (int r = 0; r < 4; ++r) {
                const int m = wv*16 + lg*4 + r;
                if (m < NM)
                    out[(size_t)(bt*NM + m)*3 + lr] = acc[r] + bb;
            }
        }
    }
}

// ---------------------------------------------------------------------------
extern "C" void kernel_launch(void* const* d_in, const int* in_sizes, int n_in,
                              void* d_out, int out_size, void* d_ws, size_t ws_size,
                              hipStream_t stream)
{
    const float* x      = (const float*)d_in[0];
    const float* seeds  = (const float*)d_in[1];
    const float* w1     = (const float*)d_in[2];
    const float* b1     = (const float*)d_in[3];
    const float* w2     = (const float*)d_in[4];
    const float* b2     = (const float*)d_in[5];
    const float* wqkv   = (const float*)d_in[6];
    const float* wout   = (const float*)d_in[7];
    const float* bout   = (const float*)d_in[8];
    const float* wc1    = (const float*)d_in[9];
    const float* cb1    = (const float*)d_in[10];
    const float* wc2    = (const float*)d_in[11];
    const float* cb2    = (const float*)d_in[12];
    const float* wproj  = (const float*)d_in[13];
    const float* bproj  = (const float*)d_in[14];
    const float* codebook = (const float*)d_in[15];
    const float* winit  = (const float*)d_in[16];
    const float* binit  = (const float*)d_in[17];
    const float* wdc1   = (const float*)d_in[18];
    const float* bdc1   = (const float*)d_in[19];
    const float* wdc2   = (const float*)d_in[20];
    const float* bdc2   = (const float*)d_in[21];
    const float* g1     = (const float*)d_in[22];
    const float* gb1    = (const float*)d_in[23];
    const float* g2     = (const float*)d_in[24];
    const float* gb2    = (const float*)d_in[25];
    const float* g3     = (const float*)d_in[26];
    const float* gb3    = (const float*)d_in[27];

    float* ws     = (float*)d_ws;
    float* hbar   = ws;                    // 1,048,576 f
    float* zbuf   = ws + 1048576;          //   262,144 f
    float* wc1T   = ws + 1310720;          //   196,608 f
    float* wc2T   = ws + 1507328;          //   196,608 f
    float* dclass = ws + 1703936;          //     1,280 f
    float* accp   = ws + 1705216;          //         4 f
    short* w2T    = (short*)(ws + 1705220);   //  65,536 bf16
    short* wqkT   = (short*)(ws + 1737988);   // 262,144 bf16
    short* g1T    = (short*)(ws + 1869060);   //  65,536 bf16
    short* g2T    = (short*)(ws + 1901828);   //  65,536 bf16
    short* g3T    = (short*)(ws + 1934596);   //   4,096 bf16
    // end ~1,936,644 floats = 7.75 MB

    float* out = (float*)d_out;

    hipMemsetAsync(accp, 0, sizeof(float), stream);
    k_prep_bf16<<<1808, 256, 0, stream>>>(w2, wqkv, g1, g2, g3, w2T, wqkT, g1T, g2T, g3T);
    k_transpose_conv<<<768, 256, 0, stream>>>(wc1, wc1T);
    k_transpose_conv<<<768, 256, 0, stream>>>(wc2, wc2T);
    k_dec_prefix<<<1, 256, 0, stream>>>(codebook, winit, binit, wdc1, bdc1, wdc2, bdc2, dclass);
    k_enc_attn<<<BTT, 256, 0, stream>>>(x, w1, b1, b2, w2T, wqkT, wqkv, wout, bout, hbar);
    k_enc_conv<<<dim3(8, 32), 256, 0, stream>>>(hbar, wc1T, cb1, wc2T, cb2, wproj, bproj, zbuf);
    k_vq_reduce<<<256, 256, 0, stream>>>(zbuf, codebook, accp);
    k_vq_final<<<1, 64, 0, stream>>>(accp, out, out_size);
    k_dec_gen<<<BTT, 256, 0, stream>>>(seeds, dclass, g1T, gb1, g2T, gb2, g3T, gb3, out);
}